// Round 2
// baseline (254.106 us; speedup 1.0000x reference)
//
#include <hip/hip_runtime.h>
#include <cstdint>
#include <cstddef>

// Problem constants (fixed by the bench harness)
#define B_ 2
#define N_ 16384
#define K_ 16
#define C_ 128

// ---------------------------------------------------------------------------
// Kernel 1: QKV projections, output TRANSPOSED to [B][N][C] in workspace.
//   Out[b][n][o] = sum_c W[o][c] * X[b][c][n]  (+ bias for V)
// grid (N/64, B, 3): z=0 -> Q (X=spa,W=wq), z=1 -> K (spe,wk), z=2 -> V (spe,wv,+b)
// block 256 threads: tile 128 o x 64 n, micro-tile 8o x 4n per thread.
// ---------------------------------------------------------------------------
__global__ __launch_bounds__(256) void qkv_gemm(
    const float* __restrict__ spa, const float* __restrict__ spe,
    const float* __restrict__ wq, const float* __restrict__ wk,
    const float* __restrict__ wv, const float* __restrict__ wvb,
    float* __restrict__ Qt, float* __restrict__ Kt, float* __restrict__ Vt)
{
    const int nt    = blockIdx.x * 64;
    const int b     = blockIdx.y;
    const int which = blockIdx.z;
    const float* X = (which == 0) ? spa : spe;
    const float* W = (which == 0) ? wq : (which == 1 ? wk : wv);
    float* Out     = (which == 0) ? Qt : (which == 1 ? Kt : Vt);

    // xs: X chunk [32 c][64 n] (+pad->68 keeps float4 16B-aligned, 2-way-max banks)
    // wst: W chunk TRANSPOSED [32 c][128 o] (+pad->132) so compute reads are b128
    __shared__ float xs[32][68];
    __shared__ float wst[32][132];

    const int t  = threadIdx.x;
    const int tx = t & 15, ty = t >> 4;
    const int o0 = ty * 8, nl0 = tx * 4;

    float acc[8][4];
    #pragma unroll
    for (int i = 0; i < 8; ++i)
        #pragma unroll
        for (int j = 0; j < 4; ++j) acc[i][j] = 0.f;

    for (int cc = 0; cc < C_; cc += 32) {
        // ---- stage X chunk: rows cc..cc+31, cols nt..nt+63 (8 floats/thread)
        {
            const int r   = t >> 3;            // 0..31
            const int col = (t & 7) * 8;       // 0..56
            const float4* src = (const float4*)(X + ((size_t)b * C_ + cc + r) * N_ + nt + col);
            float4 v0 = src[0], v1 = src[1];
            *(float4*)&xs[r][col]     = v0;
            *(float4*)&xs[r][col + 4] = v1;
        }
        // ---- stage W chunk transposed: W[o][cc..cc+31] -> wst[c][o] (16/thread)
        {
            const int r  = t >> 1;             // o row 0..127
            const int cb = (t & 1) * 16;       // col half
            const float4* src = (const float4*)(W + (size_t)r * C_ + cc + cb);
            float tmp[16];
            #pragma unroll
            for (int q = 0; q < 4; ++q) {
                float4 v = src[q];
                tmp[q*4+0] = v.x; tmp[q*4+1] = v.y; tmp[q*4+2] = v.z; tmp[q*4+3] = v.w;
            }
            #pragma unroll
            for (int m = 0; m < 16; ++m) wst[cb + m][r] = tmp[m];
        }
        __syncthreads();

        #pragma unroll
        for (int c = 0; c < 32; ++c) {
            float4 xv  = *(const float4*)&xs[c][nl0];
            float4 wlo = *(const float4*)&wst[c][o0];
            float4 whi = *(const float4*)&wst[c][o0 + 4];
            const float wr[8] = {wlo.x, wlo.y, wlo.z, wlo.w, whi.x, whi.y, whi.z, whi.w};
            const float xr[4] = {xv.x, xv.y, xv.z, xv.w};
            #pragma unroll
            for (int i = 0; i < 8; ++i)
                #pragma unroll
                for (int j = 0; j < 4; ++j)
                    acc[i][j] = fmaf(wr[i], xr[j], acc[i][j]);
        }
        __syncthreads();
    }

    if (which == 2) {
        #pragma unroll
        for (int i = 0; i < 8; ++i) {
            float bv = wvb[o0 + i];
            #pragma unroll
            for (int j = 0; j < 4; ++j) acc[i][j] += bv;
        }
    }

    // store transposed: Out[b][n][o]
    #pragma unroll
    for (int j = 0; j < 4; ++j) {
        const int n = nt + nl0 + j;
        float* dst = Out + ((size_t)b * N_ + n) * C_ + o0;
        *(float4*)dst       = make_float4(acc[0][j], acc[1][j], acc[2][j], acc[3][j]);
        *(float4*)(dst + 4) = make_float4(acc[4][j], acc[5][j], acc[6][j], acc[7][j]);
    }
}

// ---------------------------------------------------------------------------
// Kernel 2: neighbor gather + scores + softmax + weighted V-sum.
// block = 256 threads = 4 waves; block handles 32 consecutive n of one batch.
// Per wave, per n: 64 lanes = 16 k-groups x 4 lanes.
//   - 4-lane group: Q.K dot over 128 ch (float4), shfl_xor(1,2) reduce
//   - pos/sc MLPs computed redundantly in all lanes (tiny)
//   - softmax over 16 groups: shfl_xor butterfly (4,8,16,32)
//   - fusion: lane c / c+64, coalesced V reads; stage out tile in LDS,
//     final coalesced transposed store to out[B][C][N].
// ---------------------------------------------------------------------------
__global__ __launch_bounds__(256) void attn_fuse(
    const float* __restrict__ coord, const int* __restrict__ nbr,
    const float* __restrict__ Qt, const float* __restrict__ Kt,
    const float* __restrict__ Vt,
    const float* __restrict__ pw1, const float* __restrict__ pb1,
    const float* __restrict__ pg,  const float* __restrict__ pbeta,
    const float* __restrict__ pmu, const float* __restrict__ pvar,
    const float* __restrict__ pw2, const float* __restrict__ pb2,
    const float* __restrict__ sw1, const float* __restrict__ sb1,
    const float* __restrict__ sg,  const float* __restrict__ sbeta,
    const float* __restrict__ smu, const float* __restrict__ svar,
    const float* __restrict__ sw2, const float* __restrict__ sb2,
    float* __restrict__ out)
{
    const int bid  = blockIdx.x;
    const int b    = bid >> 9;              // N/32 = 512 blocks per batch
    const int n0   = (bid & 511) * 32;
    const int t    = threadIdx.x;
    const int w    = t >> 6;
    const int lane = t & 63;
    const int g    = lane >> 2;             // k index 0..15
    const int sub  = lane & 3;              // channel quarter

    __shared__ float ot[128][33];           // 33 = pad (33 % 32 == 1 -> 2-way max)

    // ---- small params (uniform across threads; BN folded to affine) ----
    float pinv[3], pofs[3], w1r[3][3], w2r[3], pb1r[3];
    #pragma unroll
    for (int o = 0; o < 3; ++o) {
        float inv = pg[o] / sqrtf(pvar[o] + 1e-5f);
        pinv[o] = inv;
        pofs[o] = pbeta[o] - pmu[o] * inv;
        pb1r[o] = pb1[o];
        w2r[o]  = pw2[o];
        #pragma unroll
        for (int i2 = 0; i2 < 3; ++i2) w1r[o][i2] = pw1[o * 3 + i2];
    }
    const float pb2v = pb2[0];
    float sinv[2], sofs[2], sb1r[2];
    #pragma unroll
    for (int o = 0; o < 2; ++o) {
        float inv = sg[o] / sqrtf(svar[o] + 1e-5f);
        sinv[o] = inv;
        sofs[o] = sbeta[o] - smu[o] * inv;
        sb1r[o] = sb1[o];
    }
    const float sw1r[4] = {sw1[0], sw1[1], sw1[2], sw1[3]};
    const float sw2r[2] = {sw2[0], sw2[1]};
    const float sb2v = sb2[0];
    const float inv_sqrtC = 0.088388347648318447f;  // 1/sqrt(128)

    for (int i = 0; i < 8; ++i) {
        const int n = n0 + w * 8 + i;
        const int idx = nbr[((size_t)b * N_ + n) * K_ + g];

        // ---- feature score: dot(Q[b,:,n], K[b,:,idx]) over this lane's 32 ch
        const float4* qp = (const float4*)(Qt + ((size_t)b * N_ + n)   * C_ + sub * 32);
        const float4* kp = (const float4*)(Kt + ((size_t)b * N_ + idx) * C_ + sub * 32);
        float acc = 0.f;
        #pragma unroll
        for (int j = 0; j < 8; ++j) {
            float4 q = qp[j], k4 = kp[j];
            acc = fmaf(q.x, k4.x, acc); acc = fmaf(q.y, k4.y, acc);
            acc = fmaf(q.z, k4.z, acc); acc = fmaf(q.w, k4.w, acc);
        }
        acc += __shfl_xor(acc, 1);
        acc += __shfl_xor(acc, 2);
        const float sfeat = acc * inv_sqrtC;

        // ---- positional score
        const float* cc = coord + ((size_t)b * N_ + n)   * 3;
        const float* nc = coord + ((size_t)b * N_ + idx) * 3;
        float d0 = nc[0] - cc[0], d1 = nc[1] - cc[1], d2 = nc[2] - cc[2];
        float g0 = expf(-2.f * d0 * d0);
        float g1 = expf(-2.f * d1 * d1);
        float g2 = expf(-2.f * d2 * d2);
        float h0 = fmaf(w1r[0][0], g0, fmaf(w1r[0][1], g1, fmaf(w1r[0][2], g2, pb1r[0])));
        float h1 = fmaf(w1r[1][0], g0, fmaf(w1r[1][1], g1, fmaf(w1r[1][2], g2, pb1r[1])));
        float h2 = fmaf(w1r[2][0], g0, fmaf(w1r[2][1], g1, fmaf(w1r[2][2], g2, pb1r[2])));
        h0 = fmaxf(fmaf(h0, pinv[0], pofs[0]), 0.f);
        h1 = fmaxf(fmaf(h1, pinv[1], pofs[1]), 0.f);
        h2 = fmaxf(fmaf(h2, pinv[2], pofs[2]), 0.f);
        const float scoord = fmaf(w2r[0], h0, fmaf(w2r[1], h1, fmaf(w2r[2], h2, pb2v)));

        // ---- score-combine MLP (2->2->1)
        float t0 = fmaf(sw1r[0], scoord, fmaf(sw1r[1], sfeat, sb1r[0]));
        t0 = fmaxf(fmaf(t0, sinv[0], sofs[0]), 0.f);
        float t1 = fmaf(sw1r[2], scoord, fmaf(sw1r[3], sfeat, sb1r[1]));
        t1 = fmaxf(fmaf(t1, sinv[1], sofs[1]), 0.f);
        float s = fmaf(sw2r[0], t0, fmaf(sw2r[1], t1, sb2v));

        // ---- softmax over the 16 k-groups (all lanes end with their k's attn)
        float m = s;
        m = fmaxf(m, __shfl_xor(m, 4));
        m = fmaxf(m, __shfl_xor(m, 8));
        m = fmaxf(m, __shfl_xor(m, 16));
        m = fmaxf(m, __shfl_xor(m, 32));
        float e = expf(s - m);
        float den = e;
        den += __shfl_xor(den, 4);
        den += __shfl_xor(den, 8);
        den += __shfl_xor(den, 16);
        den += __shfl_xor(den, 32);
        const float attn = e / den;

        // ---- fusion: sum_k attn_k * V[b, idx_k, c], lane owns c=lane, lane+64
        float a0 = 0.f, a1 = 0.f;
        #pragma unroll
        for (int k = 0; k < 16; ++k) {
            const float a = __shfl(attn, k << 2);
            const int  id = __shfl(idx,  k << 2);
            const float* vp = Vt + ((size_t)b * N_ + id) * C_;
            a0 = fmaf(a, vp[lane],      a0);
            a1 = fmaf(a, vp[lane + 64], a1);
        }
        ot[lane][w * 8 + i]      = a0;
        ot[lane + 64][w * 8 + i] = a1;
    }
    __syncthreads();

    // ---- coalesced transposed store: out[b][c][n0+col]
    {
        const int col = t & 31;
        const int r0  = (t >> 5) * 16;
        #pragma unroll
        for (int r = 0; r < 16; ++r)
            out[((size_t)b * C_ + r0 + r) * N_ + n0 + col] = ot[r0 + r][col];
    }
}

// ---------------------------------------------------------------------------
extern "C" void kernel_launch(void* const* d_in, const int* in_sizes, int n_in,
                              void* d_out, int out_size, void* d_ws, size_t ws_size,
                              hipStream_t stream) {
    const float* coord = (const float*)d_in[0];
    const float* spa   = (const float*)d_in[1];
    const float* spe   = (const float*)d_in[2];
    const int*   nbr   = (const int*)  d_in[3];
    const float* wq    = (const float*)d_in[4];
    const float* wk    = (const float*)d_in[5];
    const float* wv    = (const float*)d_in[6];
    const float* wvb   = (const float*)d_in[7];
    const float* pw1   = (const float*)d_in[8];
    const float* pb1   = (const float*)d_in[9];
    const float* pg    = (const float*)d_in[10];
    const float* pbeta = (const float*)d_in[11];
    const float* pmu   = (const float*)d_in[12];
    const float* pvar  = (const float*)d_in[13];
    const float* pw2   = (const float*)d_in[14];
    const float* pb2   = (const float*)d_in[15];
    const float* sw1   = (const float*)d_in[16];
    const float* sb1   = (const float*)d_in[17];
    const float* sg    = (const float*)d_in[18];
    const float* sbeta = (const float*)d_in[19];
    const float* smu   = (const float*)d_in[20];
    const float* svar  = (const float*)d_in[21];
    const float* sw2   = (const float*)d_in[22];
    const float* sb2   = (const float*)d_in[23];
    float* out = (float*)d_out;

    // Workspace: Q,K,V transposed [B][N][C] fp32 -> 3 * 16 MiB = 48 MiB
    float* Qt = (float*)d_ws;
    float* Kt = Qt + (size_t)B_ * N_ * C_;
    float* Vt = Kt + (size_t)B_ * N_ * C_;

    qkv_gemm<<<dim3(N_ / 64, B_, 3), 256, 0, stream>>>(
        spa, spe, wq, wk, wv, wvb, Qt, Kt, Vt);

    attn_fuse<<<dim3(B_ * N_ / 32), 256, 0, stream>>>(
        coord, nbr, Qt, Kt, Vt,
        pw1, pb1, pg, pbeta, pmu, pvar, pw2, pb2,
        sw1, sb1, sg, sbeta, smu, svar, sw2, sb2,
        out);
}

// Round 4
// 215.730 us; speedup vs baseline: 1.1779x; 1.1779x over previous
//
#include <hip/hip_runtime.h>
#include <cstdint>
#include <cstddef>

// Problem constants (fixed by the bench harness)
#define B_ 2
#define N_ 16384
#define K_ 16
#define C_ 128

// bf16 (stored as ushort) -> fp32, exact
__device__ __forceinline__ float bfu_lo(uint32_t w) { return __uint_as_float(w << 16); }
__device__ __forceinline__ float bfu_hi(uint32_t w) { return __uint_as_float(w & 0xffff0000u); }

// fp32 -> bf16 bits, round-to-nearest-even (no NaN inputs in this problem)
__device__ __forceinline__ ushort f32_to_bf16_rne(float x) {
    uint32_t u = __float_as_uint(x);
    u += 0x7FFFu + ((u >> 16) & 1u);
    return (ushort)(u >> 16);
}

// ---------------------------------------------------------------------------
// Kernel 1: QKV projections, output TRANSPOSED to [B][N][C] in workspace.
//   Q -> fp32 (exact, read once streaming); K,V -> bf16 (halves gather bytes).
// grid (N/64, B, 3): z=0 -> Q (spa,wq), z=1 -> K (spe,wk), z=2 -> V (spe,wv,+b)
// block 256 threads: tile 128 o x 64 n, micro-tile 8o x 4n per thread.
// ---------------------------------------------------------------------------
__global__ __launch_bounds__(256) void qkv_gemm(
    const float* __restrict__ spa, const float* __restrict__ spe,
    const float* __restrict__ wq, const float* __restrict__ wk,
    const float* __restrict__ wv, const float* __restrict__ wvb,
    float* __restrict__ Qt, ushort* __restrict__ Kt16, ushort* __restrict__ Vt16)
{
    const int nt    = blockIdx.x * 64;
    const int b     = blockIdx.y;
    const int which = blockIdx.z;
    const float* X = (which == 0) ? spa : spe;
    const float* W = (which == 0) ? wq : (which == 1 ? wk : wv);

    __shared__ float xs[32][68];     // X chunk [32 c][64 n] (+pad)
    __shared__ float wst[32][132];   // W chunk transposed [32 c][128 o] (+pad)

    const int t  = threadIdx.x;
    const int tx = t & 15, ty = t >> 4;
    const int o0 = ty * 8, nl0 = tx * 4;

    float acc[8][4];
    #pragma unroll
    for (int i = 0; i < 8; ++i)
        #pragma unroll
        for (int j = 0; j < 4; ++j) acc[i][j] = 0.f;

    for (int cc = 0; cc < C_; cc += 32) {
        {
            const int r   = t >> 3;
            const int col = (t & 7) * 8;
            const float4* src = (const float4*)(X + ((size_t)b * C_ + cc + r) * N_ + nt + col);
            float4 v0 = src[0], v1 = src[1];
            *(float4*)&xs[r][col]     = v0;
            *(float4*)&xs[r][col + 4] = v1;
        }
        {
            const int r  = t >> 1;
            const int cb = (t & 1) * 16;
            const float4* src = (const float4*)(W + (size_t)r * C_ + cc + cb);
            float tmp[16];
            #pragma unroll
            for (int q = 0; q < 4; ++q) {
                float4 v = src[q];
                tmp[q*4+0] = v.x; tmp[q*4+1] = v.y; tmp[q*4+2] = v.z; tmp[q*4+3] = v.w;
            }
            #pragma unroll
            for (int m = 0; m < 16; ++m) wst[cb + m][r] = tmp[m];
        }
        __syncthreads();

        #pragma unroll
        for (int c = 0; c < 32; ++c) {
            float4 xv  = *(const float4*)&xs[c][nl0];
            float4 wlo = *(const float4*)&wst[c][o0];
            float4 whi = *(const float4*)&wst[c][o0 + 4];
            const float wr[8] = {wlo.x, wlo.y, wlo.z, wlo.w, whi.x, whi.y, whi.z, whi.w};
            const float xr[4] = {xv.x, xv.y, xv.z, xv.w};
            #pragma unroll
            for (int i = 0; i < 8; ++i)
                #pragma unroll
                for (int j = 0; j < 4; ++j)
                    acc[i][j] = fmaf(wr[i], xr[j], acc[i][j]);
        }
        __syncthreads();
    }

    if (which == 2) {
        #pragma unroll
        for (int i = 0; i < 8; ++i) {
            float bv = wvb[o0 + i];
            #pragma unroll
            for (int j = 0; j < 4; ++j) acc[i][j] += bv;
        }
    }

    if (which == 0) {
        // fp32 store: Qt[b][n][o]
        #pragma unroll
        for (int j = 0; j < 4; ++j) {
            const int n = nt + nl0 + j;
            float* dst = Qt + ((size_t)b * N_ + n) * C_ + o0;
            *(float4*)dst       = make_float4(acc[0][j], acc[1][j], acc[2][j], acc[3][j]);
            *(float4*)(dst + 4) = make_float4(acc[4][j], acc[5][j], acc[6][j], acc[7][j]);
        }
    } else {
        ushort* Out16 = (which == 1) ? Kt16 : Vt16;
        #pragma unroll
        for (int j = 0; j < 4; ++j) {
            const int n = nt + nl0 + j;
            union { ushort us[8]; uint4 v; } pk;
            #pragma unroll
            for (int i = 0; i < 8; ++i)
                pk.us[i] = f32_to_bf16_rne(acc[i][j]);
            *(uint4*)(Out16 + ((size_t)b * N_ + n) * C_ + o0) = pk.v;
        }
    }
}

// ---------------------------------------------------------------------------
// Kernel 2: neighbor gather + scores + softmax + weighted V-sum.
// block = 512 threads = 8 waves; block handles 32 consecutive n (4 per wave).
// Per wave, per n: 64 lanes = 16 k-groups x 4 lanes.
//   - 4-lane group: Q(f32).K(bf16) dot over 128 ch, shfl_xor(1,2) reduce
//   - pos/sc MLPs redundantly in all lanes (tiny)
//   - softmax over 16 groups: shfl_xor butterfly (4,8,16,32)
//   - fusion: lane c / c+64 over bf16 V; LDS transpose tile; coalesced store.
// ---------------------------------------------------------------------------
__global__ __launch_bounds__(512) void attn_fuse(
    const float* __restrict__ coord, const int* __restrict__ nbr,
    const float* __restrict__ Qt, const ushort* __restrict__ Kt16,
    const ushort* __restrict__ Vt16,
    const float* __restrict__ pw1, const float* __restrict__ pb1,
    const float* __restrict__ pg,  const float* __restrict__ pbeta,
    const float* __restrict__ pmu, const float* __restrict__ pvar,
    const float* __restrict__ pw2, const float* __restrict__ pb2,
    const float* __restrict__ sw1, const float* __restrict__ sb1,
    const float* __restrict__ sg,  const float* __restrict__ sbeta,
    const float* __restrict__ smu, const float* __restrict__ svar,
    const float* __restrict__ sw2, const float* __restrict__ sb2,
    float* __restrict__ out)
{
    const int bid  = blockIdx.x;
    const int b    = bid >> 9;              // 512 blocks per batch
    const int n0   = (bid & 511) * 32;
    const int t    = threadIdx.x;
    const int w    = t >> 6;                // wave 0..7
    const int lane = t & 63;
    const int g    = lane >> 2;             // k index 0..15
    const int sub  = lane & 3;              // channel quarter

    __shared__ float ot[128][33];

    // ---- small params (uniform; BN folded to affine) ----
    float pinv[3], pofs[3], w1r[3][3], w2r[3], pb1r[3];
    #pragma unroll
    for (int o = 0; o < 3; ++o) {
        float inv = pg[o] / sqrtf(pvar[o] + 1e-5f);
        pinv[o] = inv;
        pofs[o] = pbeta[o] - pmu[o] * inv;
        pb1r[o] = pb1[o];
        w2r[o]  = pw2[o];
        #pragma unroll
        for (int i2 = 0; i2 < 3; ++i2) w1r[o][i2] = pw1[o * 3 + i2];
    }
    const float pb2v = pb2[0];
    float sinv[2], sofs[2], sb1r[2];
    #pragma unroll
    for (int o = 0; o < 2; ++o) {
        float inv = sg[o] / sqrtf(svar[o] + 1e-5f);
        sinv[o] = inv;
        sofs[o] = sbeta[o] - smu[o] * inv;
        sb1r[o] = sb1[o];
    }
    const float sw1r[4] = {sw1[0], sw1[1], sw1[2], sw1[3]};
    const float sw2r[2] = {sw2[0], sw2[1]};
    const float sb2v = sb2[0];
    const float inv_sqrtC = 0.088388347648318447f;  // 1/sqrt(128)

    #pragma unroll
    for (int i = 0; i < 4; ++i) {
        const int n = n0 + w * 4 + i;
        const int idx = nbr[((size_t)b * N_ + n) * K_ + g];

        // ---- feature score: dot(Q[n], K[idx]) over this lane's 32 channels
        const float4* qp = (const float4*)(Qt + ((size_t)b * N_ + n) * C_ + sub * 32);
        const uint4*  kp = (const uint4*) (Kt16 + ((size_t)b * N_ + idx) * C_ + sub * 32);
        float acc = 0.f;
        #pragma unroll
        for (int j = 0; j < 4; ++j) {          // 8 channels per iter
            uint4  kw = kp[j];
            float4 q0 = qp[2 * j], q1 = qp[2 * j + 1];
            acc = fmaf(q0.x, bfu_lo(kw.x), acc);
            acc = fmaf(q0.y, bfu_hi(kw.x), acc);
            acc = fmaf(q0.z, bfu_lo(kw.y), acc);
            acc = fmaf(q0.w, bfu_hi(kw.y), acc);
            acc = fmaf(q1.x, bfu_lo(kw.z), acc);
            acc = fmaf(q1.y, bfu_hi(kw.z), acc);
            acc = fmaf(q1.z, bfu_lo(kw.w), acc);
            acc = fmaf(q1.w, bfu_hi(kw.w), acc);
        }
        acc += __shfl_xor(acc, 1);
        acc += __shfl_xor(acc, 2);
        const float sfeat = acc * inv_sqrtC;

        // ---- positional score
        const float* cc = coord + ((size_t)b * N_ + n)   * 3;
        const float* nc = coord + ((size_t)b * N_ + idx) * 3;
        float d0 = nc[0] - cc[0], d1 = nc[1] - cc[1], d2 = nc[2] - cc[2];
        float g0 = expf(-2.f * d0 * d0);
        float g1 = expf(-2.f * d1 * d1);
        float g2 = expf(-2.f * d2 * d2);
        float h0 = fmaf(w1r[0][0], g0, fmaf(w1r[0][1], g1, fmaf(w1r[0][2], g2, pb1r[0])));
        float h1 = fmaf(w1r[1][0], g0, fmaf(w1r[1][1], g1, fmaf(w1r[1][2], g2, pb1r[1])));
        float h2 = fmaf(w1r[2][0], g0, fmaf(w1r[2][1], g1, fmaf(w1r[2][2], g2, pb1r[2])));
        h0 = fmaxf(fmaf(h0, pinv[0], pofs[0]), 0.f);
        h1 = fmaxf(fmaf(h1, pinv[1], pofs[1]), 0.f);
        h2 = fmaxf(fmaf(h2, pinv[2], pofs[2]), 0.f);
        const float scoord = fmaf(w2r[0], h0, fmaf(w2r[1], h1, fmaf(w2r[2], h2, pb2v)));

        // ---- score-combine MLP (2->2->1)
        float t0 = fmaf(sw1r[0], scoord, fmaf(sw1r[1], sfeat, sb1r[0]));
        t0 = fmaxf(fmaf(t0, sinv[0], sofs[0]), 0.f);
        float t1 = fmaf(sw1r[2], scoord, fmaf(sw1r[3], sfeat, sb1r[1]));
        t1 = fmaxf(fmaf(t1, sinv[1], sofs[1]), 0.f);
        float s = fmaf(sw2r[0], t0, fmaf(sw2r[1], t1, sb2v));

        // ---- softmax over the 16 k-groups
        float m = s;
        m = fmaxf(m, __shfl_xor(m, 4));
        m = fmaxf(m, __shfl_xor(m, 8));
        m = fmaxf(m, __shfl_xor(m, 16));
        m = fmaxf(m, __shfl_xor(m, 32));
        float e = expf(s - m);
        float den = e;
        den += __shfl_xor(den, 4);
        den += __shfl_xor(den, 8);
        den += __shfl_xor(den, 16);
        den += __shfl_xor(den, 32);
        const float attn = e / den;

        // ---- fusion: sum_k attn_k * V[idx_k, c], lane owns c=lane, lane+64
        float a0 = 0.f, a1 = 0.f;
        #pragma unroll
        for (int k = 0; k < 16; ++k) {
            const float a = __shfl(attn, k << 2);
            const int  id = __shfl(idx,  k << 2);
            const ushort* vp = Vt16 + ((size_t)b * N_ + id) * C_;
            a0 = fmaf(a, __uint_as_float(((uint32_t)vp[lane])      << 16), a0);
            a1 = fmaf(a, __uint_as_float(((uint32_t)vp[lane + 64]) << 16), a1);
        }
        ot[lane][w * 4 + i]      = a0;
        ot[lane + 64][w * 4 + i] = a1;
    }
    __syncthreads();

    // ---- coalesced transposed store: out[b][c][n0+col], 512 threads
    {
        const int col = t & 31;
        const int r0  = (t >> 5) * 8;
        #pragma unroll
        for (int r = 0; r < 8; ++r)
            out[((size_t)b * C_ + r0 + r) * N_ + n0 + col] = ot[r0 + r][col];
    }
}

// ---------------------------------------------------------------------------
extern "C" void kernel_launch(void* const* d_in, const int* in_sizes, int n_in,
                              void* d_out, int out_size, void* d_ws, size_t ws_size,
                              hipStream_t stream) {
    const float* coord = (const float*)d_in[0];
    const float* spa   = (const float*)d_in[1];
    const float* spe   = (const float*)d_in[2];
    const int*   nbr   = (const int*)  d_in[3];
    const float* wq    = (const float*)d_in[4];
    const float* wk    = (const float*)d_in[5];
    const float* wv    = (const float*)d_in[6];
    const float* wvb   = (const float*)d_in[7];
    const float* pw1   = (const float*)d_in[8];
    const float* pb1   = (const float*)d_in[9];
    const float* pg    = (const float*)d_in[10];
    const float* pbeta = (const float*)d_in[11];
    const float* pmu   = (const float*)d_in[12];
    const float* pvar  = (const float*)d_in[13];
    const float* pw2   = (const float*)d_in[14];
    const float* pb2   = (const float*)d_in[15];
    const float* sw1   = (const float*)d_in[16];
    const float* sb1   = (const float*)d_in[17];
    const float* sg    = (const float*)d_in[18];
    const float* sbeta = (const float*)d_in[19];
    const float* smu   = (const float*)d_in[20];
    const float* svar  = (const float*)d_in[21];
    const float* sw2   = (const float*)d_in[22];
    const float* sb2   = (const float*)d_in[23];
    float* out = (float*)d_out;

    // Workspace: Qt fp32 [B][N][C] (16 MiB), Kt/Vt bf16 [B][N][C] (8 MiB each)
    float*  Qt   = (float*)d_ws;
    ushort* Kt16 = (ushort*)(Qt + (size_t)B_ * N_ * C_);
    ushort* Vt16 = Kt16 + (size_t)B_ * N_ * C_;

    qkv_gemm<<<dim3(N_ / 64, B_, 3), 256, 0, stream>>>(
        spa, spe, wq, wk, wv, wvb, Qt, Kt16, Vt16);

    attn_fuse<<<dim3(B_ * N_ / 32), 512, 0, stream>>>(
        coord, nbr, Qt, Kt16, Vt16,
        pw1, pb1, pg, pbeta, pmu, pvar, pw2, pb2,
        sw1, sb1, sg, sbeta, smu, svar, sw2, sb2,
        out);
}

// Round 5
// 192.296 us; speedup vs baseline: 1.3214x; 1.1219x over previous
//
#include <hip/hip_runtime.h>
#include <cstdint>
#include <cstddef>

// Problem constants (fixed by the bench harness)
#define B_ 2
#define N_ 16384
#define K_ 16
#define C_ 128

typedef __attribute__((ext_vector_type(8))) short  bf16x8;
typedef __attribute__((ext_vector_type(4))) float  f32x4;

// bf16 (ushort bits) -> fp32, exact
__device__ __forceinline__ float bfu_lo(uint32_t w) { return __uint_as_float(w << 16); }
__device__ __forceinline__ float bfu_hi(uint32_t w) { return __uint_as_float(w & 0xffff0000u); }

// fp32 -> bf16 bits, round-to-nearest-even
__device__ __forceinline__ ushort f32_to_bf16_rne(float x) {
    uint32_t u = __float_as_uint(x);
    u += 0x7FFFu + ((u >> 16) & 1u);
    return (ushort)(u >> 16);
}

// LDS swizzle for the X tile: element offset of (n, c) in a [64 n][128 c] bf16
// tile; XOR of the 8-elem granule with (n&7) spreads the column reads across
// banks (B-frag read: 16 lanes read 16 consecutive n at the same c -> without
// swizzle this is a 16-way conflict at stride 256B).
__device__ __forceinline__ int xswz(int n, int c) {
    return n * 128 + ((((c >> 3) ^ (n & 7)) << 3) | (c & 7));
}

// ---------------------------------------------------------------------------
// Kernel 1: QKV projections via MFMA (bf16 in, fp32 acc, bf16 out).
//   Out[b][n][o] = sum_c W[o][c] * X[b][c][n]  (+ bias for V)
// MFMA orientation: D rows (M) = o, D cols (N) = n.
//   A-frag = W[o][c]: lane reads W[o0+(l&15)][c0+(l>>4)*8 ..+7]  (global, fp32->bf16)
//   B-frag = X^T:     lane reads xs[n0+(l&15)][c0+(l>>4)*8 ..+7] (LDS, swizzled)
//   D store: lane holds 4 consecutive o for n = l&15 -> packed bf16x4 stores,
//   lanes of one instr cover full 64B lines.
// grid (N/64, B, 3); block 256 = 4 waves; block tile 128o x 64n; wave 64o x 32n.
// ---------------------------------------------------------------------------
__global__ __launch_bounds__(256) void qkv_gemm(
    const float* __restrict__ spa, const float* __restrict__ spe,
    const float* __restrict__ wq, const float* __restrict__ wk,
    const float* __restrict__ wv, const float* __restrict__ wvb,
    ushort* __restrict__ Qt16, ushort* __restrict__ Kt16, ushort* __restrict__ Vt16)
{
    const int nt    = blockIdx.x * 64;
    const int b     = blockIdx.y;
    const int which = blockIdx.z;
    const float* X = (which == 0) ? spa : spe;
    const float* W = (which == 0) ? wq : (which == 1 ? wk : wv);
    ushort* Out    = (which == 0) ? Qt16 : (which == 1 ? Kt16 : Vt16);

    __shared__ ushort xs[64 * 128];   // 16 KB, swizzled [n][c] bf16

    const int t    = threadIdx.x;
    const int w    = t >> 6;          // wave 0..3
    const int lane = t & 63;
    const int l15  = lane & 15;
    const int l4   = lane >> 4;       // 0..3
    const int ow   = (w & 1) * 64;    // wave o-base
    const int nw   = (w >> 1) * 32;   // wave n-base (within tile)

    // ---- stage X tile [128 c][64 n] -> xs bf16 transposed+swizzled ----
    {
        const int c  = t >> 1;            // 0..127
        const int nh = (t & 1) * 32;      // n-half
        const float* xrow = X + ((size_t)b * C_ + c) * N_ + nt + nh;
        #pragma unroll
        for (int q = 0; q < 8; ++q) {
            float4 v = ((const float4*)xrow)[q];
            const int n = nh + q * 4;
            xs[xswz(n + 0, c)] = f32_to_bf16_rne(v.x);
            xs[xswz(n + 1, c)] = f32_to_bf16_rne(v.y);
            xs[xswz(n + 2, c)] = f32_to_bf16_rne(v.z);
            xs[xswz(n + 3, c)] = f32_to_bf16_rne(v.w);
        }
    }
    __syncthreads();

    f32x4 acc[4][2];
    #pragma unroll
    for (int of = 0; of < 4; ++of)
        #pragma unroll
        for (int nf = 0; nf < 2; ++nf)
            acc[of][nf] = (f32x4){0.f, 0.f, 0.f, 0.f};

    #pragma unroll
    for (int kc = 0; kc < 4; ++kc) {
        const int cb = kc * 32 + l4 * 8;
        // A-frags: W rows (global fp32 -> bf16x8)
        bf16x8 afr[4];
        #pragma unroll
        for (int of = 0; of < 4; ++of) {
            const int row = ow + of * 16 + l15;
            const float* wp = W + (size_t)row * C_ + cb;
            float4 wa = *(const float4*)wp;
            float4 wb = *(const float4*)(wp + 4);
            afr[of][0] = (short)f32_to_bf16_rne(wa.x);
            afr[of][1] = (short)f32_to_bf16_rne(wa.y);
            afr[of][2] = (short)f32_to_bf16_rne(wa.z);
            afr[of][3] = (short)f32_to_bf16_rne(wa.w);
            afr[of][4] = (short)f32_to_bf16_rne(wb.x);
            afr[of][5] = (short)f32_to_bf16_rne(wb.y);
            afr[of][6] = (short)f32_to_bf16_rne(wb.z);
            afr[of][7] = (short)f32_to_bf16_rne(wb.w);
        }
        // B-frags: xs (LDS, swizzled), 16B contiguous per lane
        bf16x8 bfr[2];
        #pragma unroll
        for (int nf = 0; nf < 2; ++nf) {
            const int n = nw + nf * 16 + l15;
            bfr[nf] = *(__shared__ bf16x8*)&xs[xswz(n, kc * 32 + l4 * 8)];
        }
        #pragma unroll
        for (int of = 0; of < 4; ++of)
            #pragma unroll
            for (int nf = 0; nf < 2; ++nf)
                acc[of][nf] = __builtin_amdgcn_mfma_f32_16x16x32_bf16(
                    afr[of], bfr[nf], acc[of][nf], 0, 0, 0);
    }

    // ---- epilogue: (+bias for V), pack bf16, store ----
    #pragma unroll
    for (int of = 0; of < 4; ++of) {
        const int o0r = ow + of * 16 + l4 * 4;     // 4 consecutive o
        float4 bv = make_float4(0.f, 0.f, 0.f, 0.f);
        if (which == 2) bv = *(const float4*)(wvb + o0r);
        #pragma unroll
        for (int nf = 0; nf < 2; ++nf) {
            const int n = nt + nw + nf * 16 + l15;
            uint2 pk;
            pk.x = (uint32_t)f32_to_bf16_rne(acc[of][nf][0] + bv.x)
                 | ((uint32_t)f32_to_bf16_rne(acc[of][nf][1] + bv.y) << 16);
            pk.y = (uint32_t)f32_to_bf16_rne(acc[of][nf][2] + bv.z)
                 | ((uint32_t)f32_to_bf16_rne(acc[of][nf][3] + bv.w) << 16);
            *(uint2*)(Out + ((size_t)b * N_ + n) * C_ + o0r) = pk;
        }
    }
}

// ---------------------------------------------------------------------------
// Kernel 2: gather + scores + softmax + weighted V-sum. Latency-optimized:
//  - idx/coord-center/Q staged to LDS once per block (16-n tile, 4096 blocks)
//  - per n: K-gather AND V-gather issued together (V doesn't depend on attn;
//    only the accumulate does) -> one latency exposure, ~23 loads in flight
//  - V held as 16 packed uint (bf16 pair); lane owns channels 2l, 2l+1
// block 256 = 4 waves; wave handles 4 n.
// ---------------------------------------------------------------------------
__global__ __launch_bounds__(256) void attn_fuse(
    const float* __restrict__ coord, const int* __restrict__ nbr,
    const ushort* __restrict__ Qt16, const ushort* __restrict__ Kt16,
    const ushort* __restrict__ Vt16,
    const float* __restrict__ pw1, const float* __restrict__ pb1,
    const float* __restrict__ pg,  const float* __restrict__ pbeta,
    const float* __restrict__ pmu, const float* __restrict__ pvar,
    const float* __restrict__ pw2, const float* __restrict__ pb2,
    const float* __restrict__ sw1, const float* __restrict__ sb1,
    const float* __restrict__ sg,  const float* __restrict__ sbeta,
    const float* __restrict__ smu, const float* __restrict__ svar,
    const float* __restrict__ sw2, const float* __restrict__ sb2,
    float* __restrict__ out)
{
    const int bid  = blockIdx.x;
    const int b    = bid >> 10;               // 1024 blocks per batch
    const int n0   = (bid & 1023) << 4;       // 16-n tile
    const int t    = threadIdx.x;
    const int w    = t >> 6;                  // wave 0..3
    const int lane = t & 63;
    const int g    = lane >> 2;               // k index 0..15
    const int sub  = lane & 3;                // channel quarter

    __shared__ float qs[16][132];             // Q tile fp32 (staged from bf16)
    __shared__ int   idx_s[16][16];
    __shared__ float cs[16][3];               // center coords
    __shared__ float ot[128][17];             // output tile [c][n]

    // ---- stage ----
    {
        const int n = t >> 4, c0 = (t & 15) * 8;
        uint4 qw = *(const uint4*)(Qt16 + ((size_t)(b * N_ + n0 + n)) * C_ + c0);
        qs[n][c0 + 0] = bfu_lo(qw.x); qs[n][c0 + 1] = bfu_hi(qw.x);
        qs[n][c0 + 2] = bfu_lo(qw.y); qs[n][c0 + 3] = bfu_hi(qw.y);
        qs[n][c0 + 4] = bfu_lo(qw.z); qs[n][c0 + 5] = bfu_hi(qw.z);
        qs[n][c0 + 6] = bfu_lo(qw.w); qs[n][c0 + 7] = bfu_hi(qw.w);
        idx_s[t >> 4][t & 15] = nbr[((size_t)(b * N_ + n0 + (t >> 4))) * K_ + (t & 15)];
        if (t < 48) cs[t / 3][t % 3] = coord[((size_t)(b * N_ + n0 + t / 3)) * 3 + (t % 3)];
    }
    __syncthreads();

    // ---- uniform params (BN folded) ----
    float pinv[3], pofs[3], w1r[3][3], w2r[3], pb1r[3];
    #pragma unroll
    for (int o = 0; o < 3; ++o) {
        float inv = pg[o] / sqrtf(pvar[o] + 1e-5f);
        pinv[o] = inv;
        pofs[o] = pbeta[o] - pmu[o] * inv;
        pb1r[o] = pb1[o];
        w2r[o]  = pw2[o];
        #pragma unroll
        for (int i2 = 0; i2 < 3; ++i2) w1r[o][i2] = pw1[o * 3 + i2];
    }
    const float pb2v = pb2[0];
    float sinv[2], sofs[2], sb1r[2];
    #pragma unroll
    for (int o = 0; o < 2; ++o) {
        float inv = sg[o] / sqrtf(svar[o] + 1e-5f);
        sinv[o] = inv;
        sofs[o] = sbeta[o] - smu[o] * inv;
        sb1r[o] = sb1[o];
    }
    const float sw1r[4] = {sw1[0], sw1[1], sw1[2], sw1[3]};
    const float sw2r[2] = {sw2[0], sw2[1]};
    const float sb2v = sb2[0];
    const float inv_sqrtC = 0.088388347648318447f;  // 1/sqrt(128)

    #pragma unroll
    for (int i = 0; i < 4; ++i) {
        const int nl = w * 4 + i;
        const int idxg = idx_s[nl][g];

        // ---- issue ALL gathers for this n up front ----
        const uint4* kp = (const uint4*)(Kt16 + ((size_t)(b * N_ + idxg)) * C_ + sub * 32);
        uint4 kw0 = kp[0], kw1 = kp[1], kw2 = kp[2], kw3 = kp[3];
        uint32_t vv[16];
        #pragma unroll
        for (int k = 0; k < 16; ++k) {
            const int vid = idx_s[nl][k];
            vv[k] = ((const uint32_t*)(Vt16 + ((size_t)(b * N_ + vid)) * C_))[lane];
        }
        const float* ncp = coord + ((size_t)(b * N_ + idxg)) * 3;
        const float nc0 = ncp[0], nc1 = ncp[1], nc2 = ncp[2];

        // ---- QK dot over this lane's 32 channels (Q from LDS) ----
        const float* qrow = &qs[nl][sub * 32];
        float acc = 0.f;
        #pragma unroll
        for (int j = 0; j < 4; ++j) {
            float4 qa = *(const float4*)&qrow[j * 8];
            float4 qb = *(const float4*)&qrow[j * 8 + 4];
            uint4  kwj = (j == 0) ? kw0 : (j == 1) ? kw1 : (j == 2) ? kw2 : kw3;
            acc = fmaf(qa.x, bfu_lo(kwj.x), acc);
            acc = fmaf(qa.y, bfu_hi(kwj.x), acc);
            acc = fmaf(qa.z, bfu_lo(kwj.y), acc);
            acc = fmaf(qa.w, bfu_hi(kwj.y), acc);
            acc = fmaf(qb.x, bfu_lo(kwj.z), acc);
            acc = fmaf(qb.y, bfu_hi(kwj.z), acc);
            acc = fmaf(qb.z, bfu_lo(kwj.w), acc);
            acc = fmaf(qb.w, bfu_hi(kwj.w), acc);
        }
        acc += __shfl_xor(acc, 1);
        acc += __shfl_xor(acc, 2);
        const float sfeat = acc * inv_sqrtC;

        // ---- positional score ----
        float d0 = nc0 - cs[nl][0], d1 = nc1 - cs[nl][1], d2 = nc2 - cs[nl][2];
        float g0 = expf(-2.f * d0 * d0);
        float g1 = expf(-2.f * d1 * d1);
        float g2 = expf(-2.f * d2 * d2);
        float h0 = fmaf(w1r[0][0], g0, fmaf(w1r[0][1], g1, fmaf(w1r[0][2], g2, pb1r[0])));
        float h1 = fmaf(w1r[1][0], g0, fmaf(w1r[1][1], g1, fmaf(w1r[1][2], g2, pb1r[1])));
        float h2 = fmaf(w1r[2][0], g0, fmaf(w1r[2][1], g1, fmaf(w1r[2][2], g2, pb1r[2])));
        h0 = fmaxf(fmaf(h0, pinv[0], pofs[0]), 0.f);
        h1 = fmaxf(fmaf(h1, pinv[1], pofs[1]), 0.f);
        h2 = fmaxf(fmaf(h2, pinv[2], pofs[2]), 0.f);
        const float scoord = fmaf(w2r[0], h0, fmaf(w2r[1], h1, fmaf(w2r[2], h2, pb2v)));

        // ---- score-combine MLP (2->2->1) ----
        float t0 = fmaf(sw1r[0], scoord, fmaf(sw1r[1], sfeat, sb1r[0]));
        t0 = fmaxf(fmaf(t0, sinv[0], sofs[0]), 0.f);
        float t1 = fmaf(sw1r[2], scoord, fmaf(sw1r[3], sfeat, sb1r[1]));
        t1 = fmaxf(fmaf(t1, sinv[1], sofs[1]), 0.f);
        float s = fmaf(sw2r[0], t0, fmaf(sw2r[1], t1, sb2v));

        // ---- softmax over 16 k-groups ----
        float m = s;
        m = fmaxf(m, __shfl_xor(m, 4));
        m = fmaxf(m, __shfl_xor(m, 8));
        m = fmaxf(m, __shfl_xor(m, 16));
        m = fmaxf(m, __shfl_xor(m, 32));
        float e = expf(s - m);
        float den = e;
        den += __shfl_xor(den, 4);
        den += __shfl_xor(den, 8);
        den += __shfl_xor(den, 16);
        den += __shfl_xor(den, 32);
        const float attn = e / den;

        // ---- fusion from registers: lane owns channels 2l, 2l+1 ----
        float a0 = 0.f, a1 = 0.f;
        #pragma unroll
        for (int k = 0; k < 16; ++k) {
            const float ak = __shfl(attn, k << 2);
            a0 = fmaf(ak, bfu_lo(vv[k]), a0);
            a1 = fmaf(ak, bfu_hi(vv[k]), a1);
        }
        ot[2 * lane][nl]     = a0;
        ot[2 * lane + 1][nl] = a1;
    }
    __syncthreads();

    // ---- coalesced transposed store: out[b][c][n0+col] ----
    {
        const int col = t & 15;
        const int r0  = (t >> 4) * 8;
        #pragma unroll
        for (int r = 0; r < 8; ++r)
            out[((size_t)(b * C_ + r0 + r)) * N_ + n0 + col] = ot[r0 + r][col];
    }
}

// ---------------------------------------------------------------------------
extern "C" void kernel_launch(void* const* d_in, const int* in_sizes, int n_in,
                              void* d_out, int out_size, void* d_ws, size_t ws_size,
                              hipStream_t stream) {
    const float* coord = (const float*)d_in[0];
    const float* spa   = (const float*)d_in[1];
    const float* spe   = (const float*)d_in[2];
    const int*   nbr   = (const int*)  d_in[3];
    const float* wq    = (const float*)d_in[4];
    const float* wk    = (const float*)d_in[5];
    const float* wv    = (const float*)d_in[6];
    const float* wvb   = (const float*)d_in[7];
    const float* pw1   = (const float*)d_in[8];
    const float* pb1   = (const float*)d_in[9];
    const float* pg    = (const float*)d_in[10];
    const float* pbeta = (const float*)d_in[11];
    const float* pmu   = (const float*)d_in[12];
    const float* pvar  = (const float*)d_in[13];
    const float* pw2   = (const float*)d_in[14];
    const float* pb2   = (const float*)d_in[15];
    const float* sw1   = (const float*)d_in[16];
    const float* sb1   = (const float*)d_in[17];
    const float* sg    = (const float*)d_in[18];
    const float* sbeta = (const float*)d_in[19];
    const float* smu   = (const float*)d_in[20];
    const float* svar  = (const float*)d_in[21];
    const float* sw2   = (const float*)d_in[22];
    const float* sb2   = (const float*)d_in[23];
    float* out = (float*)d_out;

    // Workspace: Qt/Kt/Vt bf16 [B][N][C] (8 MiB each)
    ushort* Qt16 = (ushort*)d_ws;
    ushort* Kt16 = Qt16 + (size_t)B_ * N_ * C_;
    ushort* Vt16 = Kt16 + (size_t)B_ * N_ * C_;

    qkv_gemm<<<dim3(N_ / 64, B_, 3), 256, 0, stream>>>(
        spa, spe, wq, wk, wv, wvb, Qt16, Kt16, Vt16);

    attn_fuse<<<dim3(B_ * N_ / 16), 256, 0, stream>>>(
        coord, nbr, Qt16, Kt16, Vt16,
        pw1, pb1, pg, pbeta, pmu, pvar, pw2, pb2,
        sw1, sb1, sg, sbeta, smu, svar, sw2, sb2,
        out);
}

// Round 6
// 173.549 us; speedup vs baseline: 1.4642x; 1.1080x over previous
//
#include <hip/hip_runtime.h>
#include <cstdint>
#include <cstddef>

// Problem constants (fixed by the bench harness)
#define B_ 2
#define N_ 16384
#define K_ 16
#define C_ 128

typedef __attribute__((ext_vector_type(8))) short  bf16x8;
typedef __attribute__((ext_vector_type(4))) float  f32x4;

// bf16 (ushort bits) -> fp32, exact
__device__ __forceinline__ float bfu_lo(uint32_t w) { return __uint_as_float(w << 16); }
__device__ __forceinline__ float bfu_hi(uint32_t w) { return __uint_as_float(w & 0xffff0000u); }

// fp32 -> bf16 bits, round-to-nearest-even
__device__ __forceinline__ ushort f32_to_bf16_rne(float x) {
    uint32_t u = __float_as_uint(x);
    u += 0x7FFFu + ((u >> 16) & 1u);
    return (ushort)(u >> 16);
}
__device__ __forceinline__ uint32_t pack_bf16x2(float lo, float hi) {
    return (uint32_t)f32_to_bf16_rne(lo) | ((uint32_t)f32_to_bf16_rne(hi) << 16);
}

// LDS swizzle: element offset of (row, c) in a [128 row][128 c] bf16 tile.
// XOR of the 8-elem c-granule with (row&7): fragment reads (16 lanes, same c,
// consecutive rows at stride 256B) spread over 8 bank-quads -> <=2-way (free).
__device__ __forceinline__ int xswz(int row, int c) {
    return row * 128 + ((((c >> 3) ^ (row & 7)) << 3) | (c & 7));
}

// ---------------------------------------------------------------------------
// Kernel 0: convert wq|wk|wv (fp32 128x128) to bf16 once.
// grid (8, 3) x 256 thr; thread converts 8 elems.
// ---------------------------------------------------------------------------
__global__ __launch_bounds__(256) void w_cvt(
    const float* __restrict__ wq, const float* __restrict__ wk,
    const float* __restrict__ wv, ushort* __restrict__ W16all)
{
    const float* src = (blockIdx.y == 0) ? wq : (blockIdx.y == 1 ? wk : wv);
    ushort* dst = W16all + (size_t)blockIdx.y * (C_ * C_);
    const int i = (blockIdx.x * 256 + threadIdx.x) * 8;
    float4 a = *(const float4*)(src + i);
    float4 b4 = *(const float4*)(src + i + 4);
    uint4 pk;
    pk.x = pack_bf16x2(a.x, a.y);
    pk.y = pack_bf16x2(a.z, a.w);
    pk.z = pack_bf16x2(b4.x, b4.y);
    pk.w = pack_bf16x2(b4.z, b4.w);
    *(uint4*)(dst + i) = pk;
}

// ---------------------------------------------------------------------------
// Kernel 1: QKV projections via MFMA (bf16 in, fp32 acc, bf16 out).
//   Out[b][n][o] = sum_c W[o][c] * X[b][c][n]  (+ bias for V)
// Block tile 128o x 128n, 512 thr = 8 waves (wave tile 32o x 64n).
// W16 (pre-converted) and X both staged in LDS once; inner loop is pure
// ds_read_b128 + MFMA. grid (N/128, B, 3).
// ---------------------------------------------------------------------------
__global__ __launch_bounds__(512) void qkv_gemm(
    const float* __restrict__ spa, const float* __restrict__ spe,
    const ushort* __restrict__ W16all, const float* __restrict__ wvb,
    ushort* __restrict__ Qt16, ushort* __restrict__ Kt16, ushort* __restrict__ Vt16)
{
    const int nt    = blockIdx.x * 128;
    const int b     = blockIdx.y;
    const int which = blockIdx.z;
    const float*  X   = (which == 0) ? spa : spe;
    const ushort* W16 = W16all + (size_t)which * (C_ * C_);
    ushort* Out       = (which == 0) ? Qt16 : (which == 1 ? Kt16 : Vt16);

    __shared__ ushort xs[128 * 128];   // X^T tile [n][c], swizzled, 32 KB
    __shared__ ushort ws[128 * 128];   // W tile [o][c], swizzled, 32 KB

    const int t    = threadIdx.x;
    const int w    = t >> 6;           // wave 0..7
    const int lane = t & 63;
    const int l15  = lane & 15;
    const int l4   = lane >> 4;        // 0..3
    const int ow   = (w & 3) * 32;     // wave o-base
    const int nw   = (w >> 2) * 64;    // wave n-base (within tile)

    // ---- stage W16 -> ws (coalesced uint4 reads, swizzled b128 writes) ----
    {
        const int r  = t >> 2;               // o row 0..127
        const int c0 = (t & 3) * 32;         // 32 c per thread
        const uint4* src = (const uint4*)(W16 + r * C_ + c0);
        #pragma unroll
        for (int q = 0; q < 4; ++q) {
            uint4 v = src[q];
            *(uint4*)&ws[xswz(r, c0 + q * 8)] = v;
        }
    }
    // ---- stage X tile [128 c][128 n] -> xs bf16 transposed+swizzled ----
    {
        const int c  = t >> 2;               // 0..127
        const int nq = (t & 3) * 32;         // 32 n per thread
        const float* xrow = X + ((size_t)b * C_ + c) * N_ + nt + nq;
        #pragma unroll
        for (int q = 0; q < 8; ++q) {
            float4 v = ((const float4*)xrow)[q];
            const int n = nq + q * 4;
            xs[xswz(n + 0, c)] = f32_to_bf16_rne(v.x);
            xs[xswz(n + 1, c)] = f32_to_bf16_rne(v.y);
            xs[xswz(n + 2, c)] = f32_to_bf16_rne(v.z);
            xs[xswz(n + 3, c)] = f32_to_bf16_rne(v.w);
        }
    }
    __syncthreads();

    f32x4 acc[2][4];
    #pragma unroll
    for (int of = 0; of < 2; ++of)
        #pragma unroll
        for (int nf = 0; nf < 4; ++nf)
            acc[of][nf] = (f32x4){0.f, 0.f, 0.f, 0.f};

    #pragma unroll
    for (int kc = 0; kc < 4; ++kc) {
        const int cb = kc * 32 + l4 * 8;
        bf16x8 afr[2];
        #pragma unroll
        for (int of = 0; of < 2; ++of)
            afr[of] = *(__shared__ bf16x8*)&ws[xswz(ow + of * 16 + l15, cb)];
        bf16x8 bfr[4];
        #pragma unroll
        for (int nf = 0; nf < 4; ++nf)
            bfr[nf] = *(__shared__ bf16x8*)&xs[xswz(nw + nf * 16 + l15, cb)];
        #pragma unroll
        for (int of = 0; of < 2; ++of)
            #pragma unroll
            for (int nf = 0; nf < 4; ++nf)
                acc[of][nf] = __builtin_amdgcn_mfma_f32_16x16x32_bf16(
                    afr[of], bfr[nf], acc[of][nf], 0, 0, 0);
    }

    // ---- epilogue: (+bias for V), pack bf16, store ----
    #pragma unroll
    for (int of = 0; of < 2; ++of) {
        const int o0r = ow + of * 16 + l4 * 4;     // 4 consecutive o
        float4 bv = make_float4(0.f, 0.f, 0.f, 0.f);
        if (which == 2) bv = *(const float4*)(wvb + o0r);
        #pragma unroll
        for (int nf = 0; nf < 4; ++nf) {
            const int n = nt + nw + nf * 16 + l15;
            uint2 pk;
            pk.x = pack_bf16x2(acc[of][nf][0] + bv.x, acc[of][nf][1] + bv.y);
            pk.y = pack_bf16x2(acc[of][nf][2] + bv.z, acc[of][nf][3] + bv.w);
            *(uint2*)(Out + ((size_t)b * N_ + n) * C_ + o0r) = pk;
        }
    }
}

// ---------------------------------------------------------------------------
// Kernel 2: gather + scores + softmax + weighted V-sum. (unchanged, round-5)
//  - idx/coord-center/Q staged to LDS once per block (16-n tile, 4096 blocks)
//  - per n: K-gather AND V-gather issued together -> one latency exposure
//  - V held as 16 packed uint (bf16 pair); lane owns channels 2l, 2l+1
// block 256 = 4 waves; wave handles 4 n.
// ---------------------------------------------------------------------------
__global__ __launch_bounds__(256) void attn_fuse(
    const float* __restrict__ coord, const int* __restrict__ nbr,
    const ushort* __restrict__ Qt16, const ushort* __restrict__ Kt16,
    const ushort* __restrict__ Vt16,
    const float* __restrict__ pw1, const float* __restrict__ pb1,
    const float* __restrict__ pg,  const float* __restrict__ pbeta,
    const float* __restrict__ pmu, const float* __restrict__ pvar,
    const float* __restrict__ pw2, const float* __restrict__ pb2,
    const float* __restrict__ sw1, const float* __restrict__ sb1,
    const float* __restrict__ sg,  const float* __restrict__ sbeta,
    const float* __restrict__ smu, const float* __restrict__ svar,
    const float* __restrict__ sw2, const float* __restrict__ sb2,
    float* __restrict__ out)
{
    const int bid  = blockIdx.x;
    const int b    = bid >> 10;               // 1024 blocks per batch
    const int n0   = (bid & 1023) << 4;       // 16-n tile
    const int t    = threadIdx.x;
    const int w    = t >> 6;                  // wave 0..3
    const int lane = t & 63;
    const int g    = lane >> 2;               // k index 0..15
    const int sub  = lane & 3;                // channel quarter

    __shared__ float qs[16][132];             // Q tile fp32 (staged from bf16)
    __shared__ int   idx_s[16][16];
    __shared__ float cs[16][3];               // center coords
    __shared__ float ot[128][17];             // output tile [c][n]

    // ---- stage ----
    {
        const int n = t >> 4, c0 = (t & 15) * 8;
        uint4 qw = *(const uint4*)(Qt16 + ((size_t)(b * N_ + n0 + n)) * C_ + c0);
        qs[n][c0 + 0] = bfu_lo(qw.x); qs[n][c0 + 1] = bfu_hi(qw.x);
        qs[n][c0 + 2] = bfu_lo(qw.y); qs[n][c0 + 3] = bfu_hi(qw.y);
        qs[n][c0 + 4] = bfu_lo(qw.z); qs[n][c0 + 5] = bfu_hi(qw.z);
        qs[n][c0 + 6] = bfu_lo(qw.w); qs[n][c0 + 7] = bfu_hi(qw.w);
        idx_s[t >> 4][t & 15] = nbr[((size_t)(b * N_ + n0 + (t >> 4))) * K_ + (t & 15)];
        if (t < 48) cs[t / 3][t % 3] = coord[((size_t)(b * N_ + n0 + t / 3)) * 3 + (t % 3)];
    }
    __syncthreads();

    // ---- uniform params (BN folded) ----
    float pinv[3], pofs[3], w1r[3][3], w2r[3], pb1r[3];
    #pragma unroll
    for (int o = 0; o < 3; ++o) {
        float inv = pg[o] / sqrtf(pvar[o] + 1e-5f);
        pinv[o] = inv;
        pofs[o] = pbeta[o] - pmu[o] * inv;
        pb1r[o] = pb1[o];
        w2r[o]  = pw2[o];
        #pragma unroll
        for (int i2 = 0; i2 < 3; ++i2) w1r[o][i2] = pw1[o * 3 + i2];
    }
    const float pb2v = pb2[0];
    float sinv[2], sofs[2], sb1r[2];
    #pragma unroll
    for (int o = 0; o < 2; ++o) {
        float inv = sg[o] / sqrtf(svar[o] + 1e-5f);
        sinv[o] = inv;
        sofs[o] = sbeta[o] - smu[o] * inv;
        sb1r[o] = sb1[o];
    }
    const float sw1r[4] = {sw1[0], sw1[1], sw1[2], sw1[3]};
    const float sw2r[2] = {sw2[0], sw2[1]};
    const float sb2v = sb2[0];
    const float inv_sqrtC = 0.088388347648318447f;  // 1/sqrt(128)

    #pragma unroll
    for (int i = 0; i < 4; ++i) {
        const int nl = w * 4 + i;
        const int idxg = idx_s[nl][g];

        // ---- issue ALL gathers for this n up front ----
        const uint4* kp = (const uint4*)(Kt16 + ((size_t)(b * N_ + idxg)) * C_ + sub * 32);
        uint4 kw0 = kp[0], kw1 = kp[1], kw2 = kp[2], kw3 = kp[3];
        uint32_t vv[16];
        #pragma unroll
        for (int k = 0; k < 16; ++k) {
            const int vid = idx_s[nl][k];
            vv[k] = ((const uint32_t*)(Vt16 + ((size_t)(b * N_ + vid)) * C_))[lane];
        }
        const float* ncp = coord + ((size_t)(b * N_ + idxg)) * 3;
        const float nc0 = ncp[0], nc1 = ncp[1], nc2 = ncp[2];

        // ---- QK dot over this lane's 32 channels (Q from LDS) ----
        const float* qrow = &qs[nl][sub * 32];
        float acc = 0.f;
        #pragma unroll
        for (int j = 0; j < 4; ++j) {
            float4 qa = *(const float4*)&qrow[j * 8];
            float4 qb = *(const float4*)&qrow[j * 8 + 4];
            uint4  kwj = (j == 0) ? kw0 : (j == 1) ? kw1 : (j == 2) ? kw2 : kw3;
            acc = fmaf(qa.x, bfu_lo(kwj.x), acc);
            acc = fmaf(qa.y, bfu_hi(kwj.x), acc);
            acc = fmaf(qa.z, bfu_lo(kwj.y), acc);
            acc = fmaf(qa.w, bfu_hi(kwj.y), acc);
            acc = fmaf(qb.x, bfu_lo(kwj.z), acc);
            acc = fmaf(qb.y, bfu_hi(kwj.z), acc);
            acc = fmaf(qb.z, bfu_lo(kwj.w), acc);
            acc = fmaf(qb.w, bfu_hi(kwj.w), acc);
        }
        acc += __shfl_xor(acc, 1);
        acc += __shfl_xor(acc, 2);
        const float sfeat = acc * inv_sqrtC;

        // ---- positional score ----
        float d0 = nc0 - cs[nl][0], d1 = nc1 - cs[nl][1], d2 = nc2 - cs[nl][2];
        float g0 = expf(-2.f * d0 * d0);
        float g1 = expf(-2.f * d1 * d1);
        float g2 = expf(-2.f * d2 * d2);
        float h0 = fmaf(w1r[0][0], g0, fmaf(w1r[0][1], g1, fmaf(w1r[0][2], g2, pb1r[0])));
        float h1 = fmaf(w1r[1][0], g0, fmaf(w1r[1][1], g1, fmaf(w1r[1][2], g2, pb1r[1])));
        float h2 = fmaf(w1r[2][0], g0, fmaf(w1r[2][1], g1, fmaf(w1r[2][2], g2, pb1r[2])));
        h0 = fmaxf(fmaf(h0, pinv[0], pofs[0]), 0.f);
        h1 = fmaxf(fmaf(h1, pinv[1], pofs[1]), 0.f);
        h2 = fmaxf(fmaf(h2, pinv[2], pofs[2]), 0.f);
        const float scoord = fmaf(w2r[0], h0, fmaf(w2r[1], h1, fmaf(w2r[2], h2, pb2v)));

        // ---- score-combine MLP (2->2->1) ----
        float t0 = fmaf(sw1r[0], scoord, fmaf(sw1r[1], sfeat, sb1r[0]));
        t0 = fmaxf(fmaf(t0, sinv[0], sofs[0]), 0.f);
        float t1 = fmaf(sw1r[2], scoord, fmaf(sw1r[3], sfeat, sb1r[1]));
        t1 = fmaxf(fmaf(t1, sinv[1], sofs[1]), 0.f);
        float s = fmaf(sw2r[0], t0, fmaf(sw2r[1], t1, sb2v));

        // ---- softmax over 16 k-groups ----
        float m = s;
        m = fmaxf(m, __shfl_xor(m, 4));
        m = fmaxf(m, __shfl_xor(m, 8));
        m = fmaxf(m, __shfl_xor(m, 16));
        m = fmaxf(m, __shfl_xor(m, 32));
        float e = expf(s - m);
        float den = e;
        den += __shfl_xor(den, 4);
        den += __shfl_xor(den, 8);
        den += __shfl_xor(den, 16);
        den += __shfl_xor(den, 32);
        const float attn = e / den;

        // ---- fusion from registers: lane owns channels 2l, 2l+1 ----
        float a0 = 0.f, a1 = 0.f;
        #pragma unroll
        for (int k = 0; k < 16; ++k) {
            const float ak = __shfl(attn, k << 2);
            a0 = fmaf(ak, bfu_lo(vv[k]), a0);
            a1 = fmaf(ak, bfu_hi(vv[k]), a1);
        }
        ot[2 * lane][nl]     = a0;
        ot[2 * lane + 1][nl] = a1;
    }
    __syncthreads();

    // ---- coalesced transposed store: out[b][c][n0+col] ----
    {
        const int col = t & 15;
        const int r0  = (t >> 4) * 8;
        #pragma unroll
        for (int r = 0; r < 8; ++r)
            out[((size_t)(b * C_ + r0 + r)) * N_ + n0 + col] = ot[r0 + r][col];
    }
}

// ---------------------------------------------------------------------------
extern "C" void kernel_launch(void* const* d_in, const int* in_sizes, int n_in,
                              void* d_out, int out_size, void* d_ws, size_t ws_size,
                              hipStream_t stream) {
    const float* coord = (const float*)d_in[0];
    const float* spa   = (const float*)d_in[1];
    const float* spe   = (const float*)d_in[2];
    const int*   nbr   = (const int*)  d_in[3];
    const float* wq    = (const float*)d_in[4];
    const float* wk    = (const float*)d_in[5];
    const float* wv    = (const float*)d_in[6];
    const float* wvb   = (const float*)d_in[7];
    const float* pw1   = (const float*)d_in[8];
    const float* pb1   = (const float*)d_in[9];
    const float* pg    = (const float*)d_in[10];
    const float* pbeta = (const float*)d_in[11];
    const float* pmu   = (const float*)d_in[12];
    const float* pvar  = (const float*)d_in[13];
    const float* pw2   = (const float*)d_in[14];
    const float* pb2   = (const float*)d_in[15];
    const float* sw1   = (const float*)d_in[16];
    const float* sb1   = (const float*)d_in[17];
    const float* sg    = (const float*)d_in[18];
    const float* sbeta = (const float*)d_in[19];
    const float* smu   = (const float*)d_in[20];
    const float* svar  = (const float*)d_in[21];
    const float* sw2   = (const float*)d_in[22];
    const float* sb2   = (const float*)d_in[23];
    float* out = (float*)d_out;

    // Workspace: Qt/Kt/Vt bf16 [B][N][C] (8 MiB each) + W16all (96 KB)
    ushort* Qt16  = (ushort*)d_ws;
    ushort* Kt16  = Qt16 + (size_t)B_ * N_ * C_;
    ushort* Vt16  = Kt16 + (size_t)B_ * N_ * C_;
    ushort* W16all = Vt16 + (size_t)B_ * N_ * C_;

    w_cvt<<<dim3(8, 3), 256, 0, stream>>>(wq, wk, wv, W16all);

    qkv_gemm<<<dim3(N_ / 128, B_, 3), 512, 0, stream>>>(
        spa, spe, W16all, wvb, Qt16, Kt16, Vt16);

    attn_fuse<<<dim3(B_ * N_ / 16), 256, 0, stream>>>(
        coord, nbr, Qt16, Kt16, Vt16,
        pw1, pb1, pg, pbeta, pmu, pvar, pw2, pb2,
        sw1, sb1, sg, sbeta, smu, svar, sw2, sb2,
        out);
}

// Round 7
// 168.800 us; speedup vs baseline: 1.5054x; 1.0281x over previous
//
#include <hip/hip_runtime.h>
#include <cstdint>
#include <cstddef>

// Problem constants (fixed by the bench harness)
#define B_ 2
#define N_ 16384
#define K_ 16
#define C_ 128

typedef __attribute__((ext_vector_type(8))) short  bf16x8;
typedef __attribute__((ext_vector_type(4))) float  f32x4;

// bf16 (ushort bits) -> fp32, exact
__device__ __forceinline__ float bfu_lo(uint32_t w) { return __uint_as_float(w << 16); }
__device__ __forceinline__ float bfu_hi(uint32_t w) { return __uint_as_float(w & 0xffff0000u); }

// fp32 -> bf16 bits, round-to-nearest-even
__device__ __forceinline__ ushort f32_to_bf16_rne(float x) {
    uint32_t u = __float_as_uint(x);
    u += 0x7FFFu + ((u >> 16) & 1u);
    return (ushort)(u >> 16);
}
__device__ __forceinline__ uint32_t pack_bf16x2(float lo, float hi) {
    return (uint32_t)f32_to_bf16_rne(lo) | ((uint32_t)f32_to_bf16_rne(hi) << 16);
}

// fp8 e5m2 via the f16-prefix trick (e5m2 = top byte of IEEE f16; no special
// builtins needed -> zero compile risk). Decode = shift + v_cvt_f32_f16.
__device__ __forceinline__ uint32_t e5m2_enc(float x) {
    union { _Float16 h; ushort u; } cv;
    cv.h = (_Float16)x;                       // RNE f32->f16 (hw)
    ushort h = (ushort)(cv.u + 0x7Fu + ((cv.u >> 8) & 1u));  // RNE to top byte
    return (uint32_t)(h >> 8) & 0xFFu;
}
__device__ __forceinline__ float e5m2_dec(uint32_t byteval) {
    union { _Float16 h; ushort u; } cv;
    cv.u = (ushort)(byteval << 8);
    return (float)cv.h;
}

// LDS swizzle: element offset of (row, c) in a [128 row][128 c] bf16 tile.
// XOR of the 8-elem c-granule with (row&7): fragment reads (16 lanes, same c,
// consecutive rows at stride 256B) spread over 8 bank-quads -> <=2-way (free).
__device__ __forceinline__ int xswz(int row, int c) {
    return row * 128 + ((((c >> 3) ^ (row & 7)) << 3) | (c & 7));
}

// ---------------------------------------------------------------------------
// Kernel 1: QKV projections via MFMA (bf16 in, fp32 acc).
//   Out[b][n][o] = sum_c W[o][c] * X[b][c][n]  (+ bias for V)
//   Q,V -> bf16; K -> fp8 e5m2 (halves the dominant random-gather bytes).
// Block tile 128o x 128n, 512 thr = 8 waves (wave tile 32o x 64n).
// W converted fp32->bf16 inline during LDS staging (w_cvt kernel folded in).
// grid (N/128, B, 3).
// ---------------------------------------------------------------------------
__global__ __launch_bounds__(512) void qkv_gemm(
    const float* __restrict__ spa, const float* __restrict__ spe,
    const float* __restrict__ wq, const float* __restrict__ wk,
    const float* __restrict__ wv, const float* __restrict__ wvb,
    ushort* __restrict__ Qt16, uint8_t* __restrict__ Kt8, ushort* __restrict__ Vt16)
{
    const int nt    = blockIdx.x * 128;
    const int b     = blockIdx.y;
    const int which = blockIdx.z;
    const float* X = (which == 0) ? spa : spe;
    const float* W = (which == 0) ? wq : (which == 1 ? wk : wv);

    __shared__ ushort xs[128 * 128];   // X^T tile [n][c], swizzled, 32 KB
    __shared__ ushort ws[128 * 128];   // W tile [o][c], swizzled, 32 KB

    const int t    = threadIdx.x;
    const int w    = t >> 6;           // wave 0..7
    const int lane = t & 63;
    const int l15  = lane & 15;
    const int l4   = lane >> 4;        // 0..3
    const int ow   = (w & 3) * 32;     // wave o-base
    const int nw   = (w >> 2) * 64;    // wave n-base (within tile)

    // ---- stage W (fp32 global) -> ws bf16 swizzled ----
    {
        const int r  = t >> 2;               // o row 0..127
        const int c0 = (t & 3) * 32;         // 32 c per thread
        const float* srcw = W + r * C_ + c0;
        #pragma unroll
        for (int q = 0; q < 4; ++q) {
            float4 a  = *(const float4*)(srcw + q * 8);
            float4 b4 = *(const float4*)(srcw + q * 8 + 4);
            uint4 pk;
            pk.x = pack_bf16x2(a.x, a.y);
            pk.y = pack_bf16x2(a.z, a.w);
            pk.z = pack_bf16x2(b4.x, b4.y);
            pk.w = pack_bf16x2(b4.z, b4.w);
            *(uint4*)&ws[xswz(r, c0 + q * 8)] = pk;
        }
    }
    // ---- stage X tile [128 c][128 n] -> xs bf16 transposed+swizzled ----
    {
        const int c  = t >> 2;               // 0..127
        const int nq = (t & 3) * 32;         // 32 n per thread
        const float* xrow = X + ((size_t)b * C_ + c) * N_ + nt + nq;
        #pragma unroll
        for (int q = 0; q < 8; ++q) {
            float4 v = ((const float4*)xrow)[q];
            const int n = nq + q * 4;
            xs[xswz(n + 0, c)] = f32_to_bf16_rne(v.x);
            xs[xswz(n + 1, c)] = f32_to_bf16_rne(v.y);
            xs[xswz(n + 2, c)] = f32_to_bf16_rne(v.z);
            xs[xswz(n + 3, c)] = f32_to_bf16_rne(v.w);
        }
    }
    __syncthreads();

    f32x4 acc[2][4];
    #pragma unroll
    for (int of = 0; of < 2; ++of)
        #pragma unroll
        for (int nf = 0; nf < 4; ++nf)
            acc[of][nf] = (f32x4){0.f, 0.f, 0.f, 0.f};

    #pragma unroll
    for (int kc = 0; kc < 4; ++kc) {
        const int cb = kc * 32 + l4 * 8;
        bf16x8 afr[2];
        #pragma unroll
        for (int of = 0; of < 2; ++of)
            afr[of] = *(__shared__ bf16x8*)&ws[xswz(ow + of * 16 + l15, cb)];
        bf16x8 bfr[4];
        #pragma unroll
        for (int nf = 0; nf < 4; ++nf)
            bfr[nf] = *(__shared__ bf16x8*)&xs[xswz(nw + nf * 16 + l15, cb)];
        #pragma unroll
        for (int of = 0; of < 2; ++of)
            #pragma unroll
            for (int nf = 0; nf < 4; ++nf)
                acc[of][nf] = __builtin_amdgcn_mfma_f32_16x16x32_bf16(
                    afr[of], bfr[nf], acc[of][nf], 0, 0, 0);
    }

    // ---- epilogue ----
    #pragma unroll
    for (int of = 0; of < 2; ++of) {
        const int o0r = ow + of * 16 + l4 * 4;     // 4 consecutive o
        if (which == 1) {
            // K -> fp8 e5m2, one uint32 per (of,nf)
            #pragma unroll
            for (int nf = 0; nf < 4; ++nf) {
                const int n = nt + nw + nf * 16 + l15;
                uint32_t w8 = e5m2_enc(acc[of][nf][0])
                            | (e5m2_enc(acc[of][nf][1]) << 8)
                            | (e5m2_enc(acc[of][nf][2]) << 16)
                            | (e5m2_enc(acc[of][nf][3]) << 24);
                *(uint32_t*)(Kt8 + ((size_t)b * N_ + n) * C_ + o0r) = w8;
            }
        } else {
            ushort* Out = (which == 0) ? Qt16 : Vt16;
            float4 bv = make_float4(0.f, 0.f, 0.f, 0.f);
            if (which == 2) bv = *(const float4*)(wvb + o0r);
            #pragma unroll
            for (int nf = 0; nf < 4; ++nf) {
                const int n = nt + nw + nf * 16 + l15;
                uint2 pk;
                pk.x = pack_bf16x2(acc[of][nf][0] + bv.x, acc[of][nf][1] + bv.y);
                pk.y = pack_bf16x2(acc[of][nf][2] + bv.z, acc[of][nf][3] + bv.w);
                *(uint2*)(Out + ((size_t)b * N_ + n) * C_ + o0r) = pk;
            }
        }
    }
}

// ---------------------------------------------------------------------------
// Kernel 2: gather + scores + softmax + weighted V-sum.
//  - idx/coord-center/Q staged to LDS once per block (16-n tile, 2048 blocks)
//  - per n: K-gather AND V-gather issued together -> one latency exposure
//  - K rows are fp8 e5m2 (128 B/row): halves gather bytes, K pool 2 MB/batch
//  - V held as 16 packed uint (bf16 pair); lane owns channels 2l, 2l+1
// block 256 = 4 waves; wave handles 4 n.
// ---------------------------------------------------------------------------
__global__ __launch_bounds__(256) void attn_fuse(
    const float* __restrict__ coord, const int* __restrict__ nbr,
    const ushort* __restrict__ Qt16, const uint8_t* __restrict__ Kt8,
    const ushort* __restrict__ Vt16,
    const float* __restrict__ pw1, const float* __restrict__ pb1,
    const float* __restrict__ pg,  const float* __restrict__ pbeta,
    const float* __restrict__ pmu, const float* __restrict__ pvar,
    const float* __restrict__ pw2, const float* __restrict__ pb2,
    const float* __restrict__ sw1, const float* __restrict__ sb1,
    const float* __restrict__ sg,  const float* __restrict__ sbeta,
    const float* __restrict__ smu, const float* __restrict__ svar,
    const float* __restrict__ sw2, const float* __restrict__ sb2,
    float* __restrict__ out)
{
    const int bid  = blockIdx.x;
    const int b    = bid >> 10;               // 1024 blocks per batch
    const int n0   = (bid & 1023) << 4;       // 16-n tile
    const int t    = threadIdx.x;
    const int w    = t >> 6;                  // wave 0..3
    const int lane = t & 63;
    const int g    = lane >> 2;               // k index 0..15
    const int sub  = lane & 3;                // channel quarter

    __shared__ float qs[16][132];             // Q tile fp32 (staged from bf16)
    __shared__ int   idx_s[16][16];
    __shared__ float cs[16][3];               // center coords
    __shared__ float ot[128][17];             // output tile [c][n]

    // ---- stage ----
    {
        const int n = t >> 4, c0 = (t & 15) * 8;
        uint4 qw = *(const uint4*)(Qt16 + ((size_t)(b * N_ + n0 + n)) * C_ + c0);
        qs[n][c0 + 0] = bfu_lo(qw.x); qs[n][c0 + 1] = bfu_hi(qw.x);
        qs[n][c0 + 2] = bfu_lo(qw.y); qs[n][c0 + 3] = bfu_hi(qw.y);
        qs[n][c0 + 4] = bfu_lo(qw.z); qs[n][c0 + 5] = bfu_hi(qw.z);
        qs[n][c0 + 6] = bfu_lo(qw.w); qs[n][c0 + 7] = bfu_hi(qw.w);
        idx_s[t >> 4][t & 15] = nbr[((size_t)(b * N_ + n0 + (t >> 4))) * K_ + (t & 15)];
        if (t < 48) cs[t / 3][t % 3] = coord[((size_t)(b * N_ + n0 + t / 3)) * 3 + (t % 3)];
    }
    __syncthreads();

    // ---- uniform params (BN folded) ----
    float pinv[3], pofs[3], w1r[3][3], w2r[3], pb1r[3];
    #pragma unroll
    for (int o = 0; o < 3; ++o) {
        float inv = pg[o] / sqrtf(pvar[o] + 1e-5f);
        pinv[o] = inv;
        pofs[o] = pbeta[o] - pmu[o] * inv;
        pb1r[o] = pb1[o];
        w2r[o]  = pw2[o];
        #pragma unroll
        for (int i2 = 0; i2 < 3; ++i2) w1r[o][i2] = pw1[o * 3 + i2];
    }
    const float pb2v = pb2[0];
    float sinv[2], sofs[2], sb1r[2];
    #pragma unroll
    for (int o = 0; o < 2; ++o) {
        float inv = sg[o] / sqrtf(svar[o] + 1e-5f);
        sinv[o] = inv;
        sofs[o] = sbeta[o] - smu[o] * inv;
        sb1r[o] = sb1[o];
    }
    const float sw1r[4] = {sw1[0], sw1[1], sw1[2], sw1[3]};
    const float sw2r[2] = {sw2[0], sw2[1]};
    const float sb2v = sb2[0];
    const float inv_sqrtC = 0.088388347648318447f;  // 1/sqrt(128)

    #pragma unroll
    for (int i = 0; i < 4; ++i) {
        const int nl = w * 4 + i;
        const int idxg = idx_s[nl][g];

        // ---- issue ALL gathers for this n up front ----
        const uint4* kp = (const uint4*)(Kt8 + ((size_t)(b * N_ + idxg)) * C_ + sub * 32);
        uint4 ka = kp[0], kb = kp[1];           // 32 fp8 channels
        uint32_t vv[16];
        #pragma unroll
        for (int k = 0; k < 16; ++k) {
            const int vid = idx_s[nl][k];
            vv[k] = ((const uint32_t*)(Vt16 + ((size_t)(b * N_ + vid)) * C_))[lane];
        }
        const float* ncp = coord + ((size_t)(b * N_ + idxg)) * 3;
        const float nc0 = ncp[0], nc1 = ncp[1], nc2 = ncp[2];

        // ---- QK dot over this lane's 32 channels (Q fp32 from LDS) ----
        const float* qrow = &qs[nl][sub * 32];
        float acc = 0.f;
        {
            const uint32_t wds[8] = {ka.x, ka.y, ka.z, ka.w, kb.x, kb.y, kb.z, kb.w};
            #pragma unroll
            for (int j = 0; j < 8; ++j) {
                const uint32_t ww = wds[j];
                acc = fmaf(qrow[j * 4 + 0], e5m2_dec(ww & 0xffu), acc);
                acc = fmaf(qrow[j * 4 + 1], e5m2_dec((ww >> 8) & 0xffu), acc);
                acc = fmaf(qrow[j * 4 + 2], e5m2_dec((ww >> 16) & 0xffu), acc);
                acc = fmaf(qrow[j * 4 + 3], e5m2_dec(ww >> 24), acc);
            }
        }
        acc += __shfl_xor(acc, 1);
        acc += __shfl_xor(acc, 2);
        const float sfeat = acc * inv_sqrtC;

        // ---- positional score ----
        float d0 = nc0 - cs[nl][0], d1 = nc1 - cs[nl][1], d2 = nc2 - cs[nl][2];
        float g0 = expf(-2.f * d0 * d0);
        float g1 = expf(-2.f * d1 * d1);
        float g2 = expf(-2.f * d2 * d2);
        float h0 = fmaf(w1r[0][0], g0, fmaf(w1r[0][1], g1, fmaf(w1r[0][2], g2, pb1r[0])));
        float h1 = fmaf(w1r[1][0], g0, fmaf(w1r[1][1], g1, fmaf(w1r[1][2], g2, pb1r[1])));
        float h2 = fmaf(w1r[2][0], g0, fmaf(w1r[2][1], g1, fmaf(w1r[2][2], g2, pb1r[2])));
        h0 = fmaxf(fmaf(h0, pinv[0], pofs[0]), 0.f);
        h1 = fmaxf(fmaf(h1, pinv[1], pofs[1]), 0.f);
        h2 = fmaxf(fmaf(h2, pinv[2], pofs[2]), 0.f);
        const float scoord = fmaf(w2r[0], h0, fmaf(w2r[1], h1, fmaf(w2r[2], h2, pb2v)));

        // ---- score-combine MLP (2->2->1) ----
        float t0 = fmaf(sw1r[0], scoord, fmaf(sw1r[1], sfeat, sb1r[0]));
        t0 = fmaxf(fmaf(t0, sinv[0], sofs[0]), 0.f);
        float t1 = fmaf(sw1r[2], scoord, fmaf(sw1r[3], sfeat, sb1r[1]));
        t1 = fmaxf(fmaf(t1, sinv[1], sofs[1]), 0.f);
        float s = fmaf(sw2r[0], t0, fmaf(sw2r[1], t1, sb2v));

        // ---- softmax over 16 k-groups ----
        float m = s;
        m = fmaxf(m, __shfl_xor(m, 4));
        m = fmaxf(m, __shfl_xor(m, 8));
        m = fmaxf(m, __shfl_xor(m, 16));
        m = fmaxf(m, __shfl_xor(m, 32));
        float e = expf(s - m);
        float den = e;
        den += __shfl_xor(den, 4);
        den += __shfl_xor(den, 8);
        den += __shfl_xor(den, 16);
        den += __shfl_xor(den, 32);
        const float attn = e / den;

        // ---- fusion from registers: lane owns channels 2l, 2l+1 ----
        float a0 = 0.f, a1 = 0.f;
        #pragma unroll
        for (int k = 0; k < 16; ++k) {
            const float ak = __shfl(attn, k << 2);
            a0 = fmaf(ak, bfu_lo(vv[k]), a0);
            a1 = fmaf(ak, bfu_hi(vv[k]), a1);
        }
        ot[2 * lane][nl]     = a0;
        ot[2 * lane + 1][nl] = a1;
    }
    __syncthreads();

    // ---- coalesced transposed store: out[b][c][n0+col] ----
    {
        const int col = t & 15;
        const int r0  = (t >> 4) * 8;
        #pragma unroll
        for (int r = 0; r < 8; ++r)
            out[((size_t)(b * C_ + r0 + r)) * N_ + n0 + col] = ot[r0 + r][col];
    }
}

// ---------------------------------------------------------------------------
extern "C" void kernel_launch(void* const* d_in, const int* in_sizes, int n_in,
                              void* d_out, int out_size, void* d_ws, size_t ws_size,
                              hipStream_t stream) {
    const float* coord = (const float*)d_in[0];
    const float* spa   = (const float*)d_in[1];
    const float* spe   = (const float*)d_in[2];
    const int*   nbr   = (const int*)  d_in[3];
    const float* wq    = (const float*)d_in[4];
    const float* wk    = (const float*)d_in[5];
    const float* wv    = (const float*)d_in[6];
    const float* wvb   = (const float*)d_in[7];
    const float* pw1   = (const float*)d_in[8];
    const float* pb1   = (const float*)d_in[9];
    const float* pg    = (const float*)d_in[10];
    const float* pbeta = (const float*)d_in[11];
    const float* pmu   = (const float*)d_in[12];
    const float* pvar  = (const float*)d_in[13];
    const float* pw2   = (const float*)d_in[14];
    const float* pb2   = (const float*)d_in[15];
    const float* sw1   = (const float*)d_in[16];
    const float* sb1   = (const float*)d_in[17];
    const float* sg    = (const float*)d_in[18];
    const float* sbeta = (const float*)d_in[19];
    const float* smu   = (const float*)d_in[20];
    const float* svar  = (const float*)d_in[21];
    const float* sw2   = (const float*)d_in[22];
    const float* sb2   = (const float*)d_in[23];
    float* out = (float*)d_out;

    // Workspace: Qt bf16 (8 MiB), Vt bf16 (8 MiB), Kt fp8 (4 MiB)
    ushort*  Qt16 = (ushort*)d_ws;
    ushort*  Vt16 = Qt16 + (size_t)B_ * N_ * C_;
    uint8_t* Kt8  = (uint8_t*)(Vt16 + (size_t)B_ * N_ * C_);

    qkv_gemm<<<dim3(N_ / 128, B_, 3), 512, 0, stream>>>(
        spa, spe, wq, wk, wv, wvb, Qt16, Kt8, Vt16);

    attn_fuse<<<dim3(B_ * N_ / 16), 256, 0, stream>>>(
        coord, nbr, Qt16, Kt8, Vt16,
        pw1, pb1, pg, pbeta, pmu, pvar, pw2, pb2,
        sw1, sb1, sg, sbeta, smu, svar, sw2, sb2,
        out);
}

// Round 9
// 168.122 us; speedup vs baseline: 1.5114x; 1.0040x over previous
//
#include <hip/hip_runtime.h>
#include <cstdint>
#include <cstddef>

// Problem constants (fixed by the bench harness)
#define B_ 2
#define N_ 16384
#define K_ 16
#define C_ 128

typedef __attribute__((ext_vector_type(8))) short  bf16x8;
typedef __attribute__((ext_vector_type(4))) float  f32x4;

// bf16 (ushort bits) -> fp32, exact
__device__ __forceinline__ float bfu_lo(uint32_t w) { return __uint_as_float(w << 16); }
__device__ __forceinline__ float bfu_hi(uint32_t w) { return __uint_as_float(w & 0xffff0000u); }

// fp32 -> bf16 bits, round-to-nearest-even
__device__ __forceinline__ ushort f32_to_bf16_rne(float x) {
    uint32_t u = __float_as_uint(x);
    u += 0x7FFFu + ((u >> 16) & 1u);
    return (ushort)(u >> 16);
}
__device__ __forceinline__ uint32_t pack_bf16x2(float lo, float hi) {
    return (uint32_t)f32_to_bf16_rne(lo) | ((uint32_t)f32_to_bf16_rne(hi) << 16);
}

// fp8 e5m2 via the f16-prefix trick (e5m2 = top byte of IEEE f16).
__device__ __forceinline__ uint32_t e5m2_enc(float x) {
    union { _Float16 h; ushort u; } cv;
    cv.h = (_Float16)x;                       // RNE f32->f16 (hw)
    ushort h = (ushort)(cv.u + 0x7Fu + ((cv.u >> 8) & 1u));  // RNE to top byte
    return (uint32_t)(h >> 8) & 0xFFu;
}
__device__ __forceinline__ float e5m2_dec(uint32_t byteval) {
    union { _Float16 h; ushort u; } cv;
    cv.u = (ushort)(byteval << 8);
    return (float)cv.h;
}

// LDS swizzle: element offset of (row, c) in a [128 row][128 c] bf16 tile.
__device__ __forceinline__ int xswz(int row, int c) {
    return row * 128 + ((((c >> 3) ^ (row & 7)) << 3) | (c & 7));
}

// ---------------------------------------------------------------------------
// Kernel 1: QKV projections via MFMA (bf16 in, fp32 acc).  (unchanged r7)
//   Q,V -> bf16; K -> fp8 e5m2. Block tile 128o x 128n, 512 thr = 8 waves.
// ---------------------------------------------------------------------------
__global__ __launch_bounds__(512) void qkv_gemm(
    const float* __restrict__ spa, const float* __restrict__ spe,
    const float* __restrict__ wq, const float* __restrict__ wk,
    const float* __restrict__ wv, const float* __restrict__ wvb,
    ushort* __restrict__ Qt16, uint8_t* __restrict__ Kt8, ushort* __restrict__ Vt16)
{
    const int nt    = blockIdx.x * 128;
    const int b     = blockIdx.y;
    const int which = blockIdx.z;
    const float* X = (which == 0) ? spa : spe;
    const float* W = (which == 0) ? wq : (which == 1 ? wk : wv);

    __shared__ ushort xs[128 * 128];
    __shared__ ushort ws[128 * 128];

    const int t    = threadIdx.x;
    const int w    = t >> 6;
    const int lane = t & 63;
    const int l15  = lane & 15;
    const int l4   = lane >> 4;
    const int ow   = (w & 3) * 32;
    const int nw   = (w >> 2) * 64;

    {
        const int r  = t >> 2;
        const int c0 = (t & 3) * 32;
        const float* srcw = W + r * C_ + c0;
        #pragma unroll
        for (int q = 0; q < 4; ++q) {
            float4 a  = *(const float4*)(srcw + q * 8);
            float4 b4 = *(const float4*)(srcw + q * 8 + 4);
            uint4 pk;
            pk.x = pack_bf16x2(a.x, a.y);
            pk.y = pack_bf16x2(a.z, a.w);
            pk.z = pack_bf16x2(b4.x, b4.y);
            pk.w = pack_bf16x2(b4.z, b4.w);
            *(uint4*)&ws[xswz(r, c0 + q * 8)] = pk;
        }
    }
    {
        const int c  = t >> 2;
        const int nq = (t & 3) * 32;
        const float* xrow = X + ((size_t)b * C_ + c) * N_ + nt + nq;
        #pragma unroll
        for (int q = 0; q < 8; ++q) {
            float4 v = ((const float4*)xrow)[q];
            const int n = nq + q * 4;
            xs[xswz(n + 0, c)] = f32_to_bf16_rne(v.x);
            xs[xswz(n + 1, c)] = f32_to_bf16_rne(v.y);
            xs[xswz(n + 2, c)] = f32_to_bf16_rne(v.z);
            xs[xswz(n + 3, c)] = f32_to_bf16_rne(v.w);
        }
    }
    __syncthreads();

    f32x4 acc[2][4];
    #pragma unroll
    for (int of = 0; of < 2; ++of)
        #pragma unroll
        for (int nf = 0; nf < 4; ++nf)
            acc[of][nf] = (f32x4){0.f, 0.f, 0.f, 0.f};

    #pragma unroll
    for (int kc = 0; kc < 4; ++kc) {
        const int cb = kc * 32 + l4 * 8;
        bf16x8 afr[2];
        #pragma unroll
        for (int of = 0; of < 2; ++of)
            afr[of] = *(__shared__ bf16x8*)&ws[xswz(ow + of * 16 + l15, cb)];
        bf16x8 bfr[4];
        #pragma unroll
        for (int nf = 0; nf < 4; ++nf)
            bfr[nf] = *(__shared__ bf16x8*)&xs[xswz(nw + nf * 16 + l15, cb)];
        #pragma unroll
        for (int of = 0; of < 2; ++of)
            #pragma unroll
            for (int nf = 0; nf < 4; ++nf)
                acc[of][nf] = __builtin_amdgcn_mfma_f32_16x16x32_bf16(
                    afr[of], bfr[nf], acc[of][nf], 0, 0, 0);
    }

    #pragma unroll
    for (int of = 0; of < 2; ++of) {
        const int o0r = ow + of * 16 + l4 * 4;
        if (which == 1) {
            #pragma unroll
            for (int nf = 0; nf < 4; ++nf) {
                const int n = nt + nw + nf * 16 + l15;
                uint32_t w8 = e5m2_enc(acc[of][nf][0])
                            | (e5m2_enc(acc[of][nf][1]) << 8)
                            | (e5m2_enc(acc[of][nf][2]) << 16)
                            | (e5m2_enc(acc[of][nf][3]) << 24);
                *(uint32_t*)(Kt8 + ((size_t)b * N_ + n) * C_ + o0r) = w8;
            }
        } else {
            ushort* Out = (which == 0) ? Qt16 : Vt16;
            float4 bv = make_float4(0.f, 0.f, 0.f, 0.f);
            if (which == 2) bv = *(const float4*)(wvb + o0r);
            #pragma unroll
            for (int nf = 0; nf < 4; ++nf) {
                const int n = nt + nw + nf * 16 + l15;
                uint2 pk;
                pk.x = pack_bf16x2(acc[of][nf][0] + bv.x, acc[of][nf][1] + bv.y);
                pk.y = pack_bf16x2(acc[of][nf][2] + bv.z, acc[of][nf][3] + bv.w);
                *(uint2*)(Out + ((size_t)b * N_ + n) * C_ + o0r) = pk;
            }
        }
    }
}

// ---------------------------------------------------------------------------
// Kernel 2: gather + scores + softmax + weighted V-sum.
// Round-8: explicit 2-deep gather pipeline across n (sets A/B, named regs):
// issue n=0,1 up front; during compute(n) the set freed by n refills for n+2.
// One full gather set (~21 loads/lane) stays in flight under every compute.
// block 256 = 4 waves; wave handles 4 n; 16-n tile per block.
// ---------------------------------------------------------------------------
struct GR {
    uint4    ka, kb;          // 32 fp8 K channels for this lane's k-group
    uint32_t vv[16];          // V bf16-pair per k, channels 2l/2l+1
    float    nc0, nc1, nc2;   // neighbor coords for this lane's k-group
};

__device__ __forceinline__ void gather_issue(
    GR& g2, const int (*idx_s)[16], int nl, int b,
    const uint8_t* __restrict__ Kt8, const ushort* __restrict__ Vt16,
    const float* __restrict__ coord, int gk, int sub, int lane)
{
    const int idxg = idx_s[nl][gk];
    const uint4* kp = (const uint4*)(Kt8 + ((size_t)(b * N_ + idxg)) * C_ + sub * 32);
    g2.ka = kp[0];
    g2.kb = kp[1];
    #pragma unroll
    for (int k = 0; k < 16; ++k) {
        const int vid = idx_s[nl][k];
        g2.vv[k] = ((const uint32_t*)(Vt16 + ((size_t)(b * N_ + vid)) * C_))[lane];
    }
    const float* ncp = coord + ((size_t)(b * N_ + idxg)) * 3;
    g2.nc0 = ncp[0];
    g2.nc1 = ncp[1];
    g2.nc2 = ncp[2];
}

__global__ __launch_bounds__(256) void attn_fuse(
    const float* __restrict__ coord, const int* __restrict__ nbr,
    const ushort* __restrict__ Qt16, const uint8_t* __restrict__ Kt8,
    const ushort* __restrict__ Vt16,
    const float* __restrict__ pw1, const float* __restrict__ pb1,
    const float* __restrict__ pg,  const float* __restrict__ pbeta,
    const float* __restrict__ pmu, const float* __restrict__ pvar,
    const float* __restrict__ pw2, const float* __restrict__ pb2,
    const float* __restrict__ sw1, const float* __restrict__ sb1,
    const float* __restrict__ sg,  const float* __restrict__ sbeta,
    const float* __restrict__ smu, const float* __restrict__ svar,
    const float* __restrict__ sw2, const float* __restrict__ sb2,
    float* __restrict__ out)
{
    const int bid  = blockIdx.x;
    const int b    = bid >> 10;               // 1024 blocks per batch
    const int n0   = (bid & 1023) << 4;       // 16-n tile
    const int t    = threadIdx.x;
    const int w    = t >> 6;                  // wave 0..3
    const int lane = t & 63;
    const int g    = lane >> 2;               // k index 0..15
    const int sub  = lane & 3;                // channel quarter

    __shared__ float qs[16][132];
    __shared__ int   idx_s[16][16];
    __shared__ float cs[16][3];
    __shared__ float ot[128][17];

    // ---- stage ----
    {
        const int n = t >> 4, c0 = (t & 15) * 8;
        uint4 qw = *(const uint4*)(Qt16 + ((size_t)(b * N_ + n0 + n)) * C_ + c0);
        qs[n][c0 + 0] = bfu_lo(qw.x); qs[n][c0 + 1] = bfu_hi(qw.x);
        qs[n][c0 + 2] = bfu_lo(qw.y); qs[n][c0 + 3] = bfu_hi(qw.y);
        qs[n][c0 + 4] = bfu_lo(qw.z); qs[n][c0 + 5] = bfu_hi(qw.z);
        qs[n][c0 + 6] = bfu_lo(qw.w); qs[n][c0 + 7] = bfu_hi(qw.w);
        idx_s[t >> 4][t & 15] = nbr[((size_t)(b * N_ + n0 + (t >> 4))) * K_ + (t & 15)];
        if (t < 48) cs[t / 3][t % 3] = coord[((size_t)(b * N_ + n0 + t / 3)) * 3 + (t % 3)];
    }
    __syncthreads();

    // ---- uniform params (BN folded) ----
    float pinv[3], pofs[3], w1r[3][3], w2r[3], pb1r[3];
    #pragma unroll
    for (int o = 0; o < 3; ++o) {
        float inv = pg[o] / sqrtf(pvar[o] + 1e-5f);
        pinv[o] = inv;
        pofs[o] = pbeta[o] - pmu[o] * inv;
        pb1r[o] = pb1[o];
        w2r[o]  = pw2[o];
        #pragma unroll
        for (int i2 = 0; i2 < 3; ++i2) w1r[o][i2] = pw1[o * 3 + i2];
    }
    const float pb2v = pb2[0];
    float sinv[2], sofs[2], sb1r[2];
    #pragma unroll
    for (int o = 0; o < 2; ++o) {
        float inv = sg[o] / sqrtf(svar[o] + 1e-5f);
        sinv[o] = inv;
        sofs[o] = sbeta[o] - smu[o] * inv;
        sb1r[o] = sb1[o];
    }
    const float sw1r[4] = {sw1[0], sw1[1], sw1[2], sw1[3]};
    const float sw2r[2] = {sw2[0], sw2[1]};
    const float sb2v = sb2[0];
    const float inv_sqrtC = 0.088388347648318447f;  // 1/sqrt(128)

    // compute for one n using a gather set (macro-ish lambda, static indexing)
    auto compute = [&](int nl, GR& gr) {
        const float* qrow = &qs[nl][sub * 32];
        float acc = 0.f;
        {
            const uint32_t wds[8] = {gr.ka.x, gr.ka.y, gr.ka.z, gr.ka.w,
                                     gr.kb.x, gr.kb.y, gr.kb.z, gr.kb.w};
            #pragma unroll
            for (int j = 0; j < 8; ++j) {
                const uint32_t ww = wds[j];
                acc = fmaf(qrow[j * 4 + 0], e5m2_dec(ww & 0xffu), acc);
                acc = fmaf(qrow[j * 4 + 1], e5m2_dec((ww >> 8) & 0xffu), acc);
                acc = fmaf(qrow[j * 4 + 2], e5m2_dec((ww >> 16) & 0xffu), acc);
                acc = fmaf(qrow[j * 4 + 3], e5m2_dec(ww >> 24), acc);
            }
        }
        acc += __shfl_xor(acc, 1);
        acc += __shfl_xor(acc, 2);
        const float sfeat = acc * inv_sqrtC;

        float d0 = gr.nc0 - cs[nl][0], d1 = gr.nc1 - cs[nl][1], d2 = gr.nc2 - cs[nl][2];
        float g0 = expf(-2.f * d0 * d0);
        float g1 = expf(-2.f * d1 * d1);
        float g2 = expf(-2.f * d2 * d2);
        float h0 = fmaf(w1r[0][0], g0, fmaf(w1r[0][1], g1, fmaf(w1r[0][2], g2, pb1r[0])));
        float h1 = fmaf(w1r[1][0], g0, fmaf(w1r[1][1], g1, fmaf(w1r[1][2], g2, pb1r[1])));
        float h2 = fmaf(w1r[2][0], g0, fmaf(w1r[2][1], g1, fmaf(w1r[2][2], g2, pb1r[2])));
        h0 = fmaxf(fmaf(h0, pinv[0], pofs[0]), 0.f);
        h1 = fmaxf(fmaf(h1, pinv[1], pofs[1]), 0.f);
        h2 = fmaxf(fmaf(h2, pinv[2], pofs[2]), 0.f);
        const float scoord = fmaf(w2r[0], h0, fmaf(w2r[1], h1, fmaf(w2r[2], h2, pb2v)));

        float t0 = fmaf(sw1r[0], scoord, fmaf(sw1r[1], sfeat, sb1r[0]));
        t0 = fmaxf(fmaf(t0, sinv[0], sofs[0]), 0.f);
        float t1 = fmaf(sw1r[2], scoord, fmaf(sw1r[3], sfeat, sb1r[1]));
        t1 = fmaxf(fmaf(t1, sinv[1], sofs[1]), 0.f);
        float s = fmaf(sw2r[0], t0, fmaf(sw2r[1], t1, sb2v));

        float m = s;
        m = fmaxf(m, __shfl_xor(m, 4));
        m = fmaxf(m, __shfl_xor(m, 8));
        m = fmaxf(m, __shfl_xor(m, 16));
        m = fmaxf(m, __shfl_xor(m, 32));
        float e = expf(s - m);
        float den = e;
        den += __shfl_xor(den, 4);
        den += __shfl_xor(den, 8);
        den += __shfl_xor(den, 16);
        den += __shfl_xor(den, 32);
        const float attn = e / den;

        float a0 = 0.f, a1 = 0.f;
        #pragma unroll
        for (int k = 0; k < 16; ++k) {
            const float ak = __shfl(attn, k << 2);
            a0 = fmaf(ak, bfu_lo(gr.vv[k]), a0);
            a1 = fmaf(ak, bfu_hi(gr.vv[k]), a1);
        }
        ot[2 * lane][nl]     = a0;
        ot[2 * lane + 1][nl] = a1;
    };

    // ---- 2-deep pipeline over the wave's 4 n ----
    GR A, B;
    gather_issue(A, idx_s, w * 4 + 0, b, Kt8, Vt16, coord, g, sub, lane);
    gather_issue(B, idx_s, w * 4 + 1, b, Kt8, Vt16, coord, g, sub, lane);
    compute(w * 4 + 0, A);
    gather_issue(A, idx_s, w * 4 + 2, b, Kt8, Vt16, coord, g, sub, lane);
    compute(w * 4 + 1, B);
    gather_issue(B, idx_s, w * 4 + 3, b, Kt8, Vt16, coord, g, sub, lane);
    compute(w * 4 + 2, A);
    compute(w * 4 + 3, B);

    __syncthreads();

    // ---- coalesced transposed store: out[b][c][n0+col] ----
    {
        const int col = t & 15;
        const int r0  = (t >> 4) * 8;
        #pragma unroll
        for (int r = 0; r < 8; ++r)
            out[((size_t)(b * C_ + r0 + r)) * N_ + n0 + col] = ot[r0 + r][col];
    }
}

// ---------------------------------------------------------------------------
extern "C" void kernel_launch(void* const* d_in, const int* in_sizes, int n_in,
                              void* d_out, int out_size, void* d_ws, size_t ws_size,
                              hipStream_t stream) {
    const float* coord = (const float*)d_in[0];
    const float* spa   = (const float*)d_in[1];
    const float* spe   = (const float*)d_in[2];
    const int*   nbr   = (const int*)  d_in[3];
    const float* wq    = (const float*)d_in[4];
    const float* wk    = (const float*)d_in[5];
    const float* wv    = (const float*)d_in[6];
    const float* wvb   = (const float*)d_in[7];
    const float* pw1   = (const float*)d_in[8];
    const float* pb1   = (const float*)d_in[9];
    const float* pg    = (const float*)d_in[10];
    const float* pbeta = (const float*)d_in[11];
    const float* pmu   = (const float*)d_in[12];
    const float* pvar  = (const float*)d_in[13];
    const float* pw2   = (const float*)d_in[14];
    const float* pb2   = (const float*)d_in[15];
    const float* sw1   = (const float*)d_in[16];
    const float* sb1   = (const float*)d_in[17];
    const float* sg    = (const float*)d_in[18];
    const float* sbeta = (const float*)d_in[19];
    const float* smu   = (const float*)d_in[20];
    const float* svar  = (const float*)d_in[21];
    const float* sw2   = (const float*)d_in[22];
    const float* sb2   = (const float*)d_in[23];
    float* out = (float*)d_out;

    // Workspace: Qt bf16 (8 MiB), Vt bf16 (8 MiB), Kt fp8 (4 MiB)
    ushort*  Qt16 = (ushort*)d_ws;
    ushort*  Vt16 = Qt16 + (size_t)B_ * N_ * C_;
    uint8_t* Kt8  = (uint8_t*)(Vt16 + (size_t)B_ * N_ * C_);

    qkv_gemm<<<dim3(N_ / 128, B_, 3), 512, 0, stream>>>(
        spa, spe, wq, wk, wv, wvb, Qt16, Kt8, Vt16);

    attn_fuse<<<dim3(B_ * N_ / 16), 256, 0, stream>>>(
        coord, nbr, Qt16, Kt8, Vt16,
        pw1, pb1, pg, pbeta, pmu, pvar, pw2, pb2,
        sw1, sb1, sg, sbeta, smu, svar, sw2, sb2,
        out);
}